// Round 2
// baseline (2935.613 us; speedup 1.0000x reference)
//
#include <hip/hip_runtime.h>
#include <hip/hip_bf16.h>
#include <math.h>

// Problem constants
constexpr int kB = 4, kT = 2048, kC = 1024;
constexpr int kH = 8, kHKV = 4, kD = 128;
constexpr int kRATIO = 4, kG = 512;
constexpr int kHI = 8, kDI = 64;
constexpr int kTOPK = 64, kRANK = 512;
constexpr float kTHETA = 160000.0f;
constexpr float kNEG = -1e30f;

// Projection buffer column layout (value path only; indexer path is fp64)
constexpr int NTOT = 2560;
constexpr int Q_OFF = 0;      // 1024 cols (H*D)
constexpr int CK_OFF = 1024;  // 512
constexpr int CV_OFF = 1536;  // 512
constexpr int CG_OFF = 2048;  // 512

__device__ inline float waveReduceSum(float v) {
    #pragma unroll
    for (int m = 32; m > 0; m >>= 1) v += __shfl_xor(v, m, 64);
    return v;
}
__device__ inline double waveReduceSumD(double v) {
    #pragma unroll
    for (int m = 32; m > 0; m >>= 1) v += __shfl_xor(v, m, 64);
    return v;
}
__device__ inline float waveReduceMax(float v) {
    #pragma unroll
    for (int m = 32; m > 0; m >>= 1) v = fmaxf(v, __shfl_xor(v, m, 64));
    return v;
}

// ---------------------------------------------------------------------------
// Tiled fp32 GEMM, C = alpha * A * B   (A: MxK rm, B: KxN rm, C: MxN rm)
// ---------------------------------------------------------------------------
#define BM 64
#define BN 64
#define BK 16

__global__ __launch_bounds__(256) void gemm_nn_kernel(
    const float* __restrict__ A, int lda,
    const float* __restrict__ B, int ldb,
    float* __restrict__ C, int ldc,
    int K, float alpha, const float* __restrict__ rowScale)
{
    __shared__ float As[BK][BM + 1];
    __shared__ float Bs[BK][BN + 4];
    const int tid = threadIdx.x;
    const int bx = blockIdx.x, by = blockIdx.y;
    const int tx = tid & 15, ty = tid >> 4;
    const int arow = tid >> 2;
    const int akq  = (tid & 3) << 2;
    const int brow = tid >> 4;
    const int bcol = (tid & 15) << 2;
    const float rsA = rowScale ? rowScale[by * BM + arow] : 1.0f;
    const float* Aptr = A + (size_t)(by * BM + arow) * lda + akq;
    const float* Bptr = B + (size_t)brow * ldb + (size_t)bx * BN + bcol;
    float acc[4][4] = {};
    for (int k0 = 0; k0 < K; k0 += BK) {
        float4 a4 = *(const float4*)(Aptr + k0);
        float4 b4 = *(const float4*)(Bptr + (size_t)k0 * ldb);
        __syncthreads();
        As[akq + 0][arow] = a4.x * rsA;
        As[akq + 1][arow] = a4.y * rsA;
        As[akq + 2][arow] = a4.z * rsA;
        As[akq + 3][arow] = a4.w * rsA;
        *(float4*)&Bs[brow][bcol] = b4;
        __syncthreads();
        #pragma unroll
        for (int kk = 0; kk < BK; ++kk) {
            float a[4];
            #pragma unroll
            for (int i = 0; i < 4; ++i) a[i] = As[kk][ty * 4 + i];
            float4 bb = *(const float4*)&Bs[kk][tx * 4];
            float b[4] = {bb.x, bb.y, bb.z, bb.w};
            #pragma unroll
            for (int i = 0; i < 4; ++i)
                #pragma unroll
                for (int j = 0; j < 4; ++j)
                    acc[i][j] = fmaf(a[i], b[j], acc[i][j]);
        }
    }
    #pragma unroll
    for (int i = 0; i < 4; ++i) {
        float4 o = make_float4(acc[i][0] * alpha, acc[i][1] * alpha,
                               acc[i][2] * alpha, acc[i][3] * alpha);
        *(float4*)&C[(size_t)(by * BM + ty * 4 + i) * ldc + bx * BN + tx * 4] = o;
    }
}

// C = alpha * A * B^T   (A: MxK rm, B: NxK rm)
__global__ __launch_bounds__(256) void gemm_nt_kernel(
    const float* __restrict__ A, int lda,
    const float* __restrict__ B, int ldb,
    float* __restrict__ C, int ldc,
    int K, float alpha)
{
    __shared__ float As[BK][BM + 1];
    __shared__ float Bs[BK][BN + 4];
    const int tid = threadIdx.x;
    const int bx = blockIdx.x, by = blockIdx.y;
    const int tx = tid & 15, ty = tid >> 4;
    const int arow = tid >> 2;
    const int akq  = (tid & 3) << 2;
    const float* Aptr = A + (size_t)(by * BM + arow) * lda + akq;
    const float* Bptr = B + (size_t)(bx * BN + arow) * ldb + akq;
    float acc[4][4] = {};
    for (int k0 = 0; k0 < K; k0 += BK) {
        float4 a4 = *(const float4*)(Aptr + k0);
        float4 b4 = *(const float4*)(Bptr + k0);
        __syncthreads();
        As[akq + 0][arow] = a4.x;
        As[akq + 1][arow] = a4.y;
        As[akq + 2][arow] = a4.z;
        As[akq + 3][arow] = a4.w;
        Bs[akq + 0][arow] = b4.x;
        Bs[akq + 1][arow] = b4.y;
        Bs[akq + 2][arow] = b4.z;
        Bs[akq + 3][arow] = b4.w;
        __syncthreads();
        #pragma unroll
        for (int kk = 0; kk < BK; ++kk) {
            float a[4];
            #pragma unroll
            for (int i = 0; i < 4; ++i) a[i] = As[kk][ty * 4 + i];
            float4 bb = *(const float4*)&Bs[kk][tx * 4];
            float b[4] = {bb.x, bb.y, bb.z, bb.w};
            #pragma unroll
            for (int i = 0; i < 4; ++i)
                #pragma unroll
                for (int j = 0; j < 4; ++j)
                    acc[i][j] = fmaf(a[i], b[j], acc[i][j]);
        }
    }
    #pragma unroll
    for (int i = 0; i < 4; ++i) {
        float4 o = make_float4(acc[i][0] * alpha, acc[i][1] * alpha,
                               acc[i][2] * alpha, acc[i][3] * alpha);
        *(float4*)&C[(size_t)(by * BM + ty * 4 + i) * ldc + bx * BN + tx * 4] = o;
    }
}

// ---------------------------------------------------------------------------
// In-place partial RoPE on the q columns of Y. One thread per (b,t,h,j<32).
// ---------------------------------------------------------------------------
__global__ __launch_bounds__(256) void rope_q_kernel(float* __restrict__ Y)
{
    int idx = blockIdx.x * 256 + threadIdx.x;
    int j = idx & 31;
    int rest = idx >> 5;
    int h = rest & 7;  rest >>= 3;
    int t = rest & (kT - 1);
    int b = rest >> 11;
    size_t base = (size_t)(b * kT + t) * NTOT + Q_OFF + h * kD;
    float inv_freq = powf(kTHETA, -(float)j * (1.0f / 32.0f));
    float ang = (float)t * inv_freq;
    float c = cosf(ang), s = sinf(ang);
    float x1 = Y[base + 64 + j];
    float x2 = Y[base + 96 + j];
    Y[base + 64 + j] = x1 * c - x2 * s;
    Y[base + 96 + j] = x1 * s + x2 * c;
}

// Gated compress for main KV + RoPE on ck. One block(128) per (b,g,h in HKV).
__global__ __launch_bounds__(128) void compress_c_kernel(
    const float* __restrict__ Y, const float* __restrict__ ape_c,
    float* __restrict__ ck, float* __restrict__ cv)
{
    int bid = blockIdx.x;
    int h = bid & 3;
    int g = (bid >> 2) & (kG - 1);
    int b = bid >> 11;
    int d = threadIdx.x;
    float kv[kRATIO], vv[kRATIO], gv[kRATIO];
    #pragma unroll
    for (int r = 0; r < kRATIO; ++r) {
        size_t row = (size_t)(b * kT + g * kRATIO + r) * NTOT;
        kv[r] = Y[row + CK_OFF + h * kD + d];
        vv[r] = Y[row + CV_OFF + h * kD + d];
        gv[r] = Y[row + CG_OFF + h * kD + d] + ape_c[(r * kHKV + h) * kD + d];
    }
    float m = fmaxf(fmaxf(gv[0], gv[1]), fmaxf(gv[2], gv[3]));
    float ka = 0.f, va = 0.f, den = 0.f;
    #pragma unroll
    for (int r = 0; r < kRATIO; ++r) {
        float e = expf(gv[r] - m);
        den += e;
        ka += kv[r] * e;
        va += vv[r] * e;
    }
    ka /= den; va /= den;
    size_t obase = ((size_t)(b * kG + g) * kHKV + h) * kD;
    cv[obase + d] = va;
    __shared__ float cks[kD];
    cks[d] = ka;
    __syncthreads();
    int pos = 4 * g + 3;
    float out;
    if (d < 64) {
        out = cks[d];
    } else if (d < 96) {
        int j = d - 64;
        float inv_freq = powf(kTHETA, -(float)j * (1.0f / 32.0f));
        float ang = (float)pos * inv_freq;
        out = cks[d] * cosf(ang) - cks[d + 32] * sinf(ang);
    } else {
        int j = d - 96;
        float inv_freq = powf(kTHETA, -(float)j * (1.0f / 32.0f));
        float ang = (float)pos * inv_freq;
        out = cks[d - 32] * sinf(ang) + cks[d] * cosf(ang);
    }
    ck[obase + d] = out;
}

// ---------------------------------------------------------------------------
// fp64 indexer chain. Selection (top-k) is a discontinuous argmax over the
// indexer scores; fp32 rounding differences vs the reference can flip the
// rank-64 boundary and blow a whole row past tolerance. Compute the entire
// chain feeding the sort in fp64 so ordering matches the reference exactly.
// ---------------------------------------------------------------------------

// iq64[row, h*64+d] = rmsnorm64(x[row] @ Wiq[:, h*64+d]); one wave per (row,h)
__global__ __launch_bounds__(64) void iq_f64_kernel(
    const float* __restrict__ x, const float* __restrict__ Wiq,
    double* __restrict__ iq64)
{
    int bid = blockIdx.x;              // row*8 + h
    int h = bid & 7;
    int row = bid >> 3;
    int lane = threadIdx.x;
    __shared__ float xs[kC];
    const float* xp = x + (size_t)row * kC;
    #pragma unroll
    for (int i = 0; i < 4; ++i)
        *(float4*)&xs[lane * 4 + i * 256] = *(const float4*)&xp[lane * 4 + i * 256];
    __syncthreads();
    const float* wp = Wiq + h * kDI + lane;
    double acc = 0.0;
    for (int c = 0; c < kC; ++c)
        acc += (double)xs[c] * (double)wp[(size_t)c * 512];
    double ss = waveReduceSumD(acc * acc);
    double scale = 1.0 / sqrt(ss * (1.0 / kDI) + 1e-6);
    iq64[(size_t)row * 512 + h * kDI + lane] = acc * scale;
}

// ikeys64: gated compress of indexer keys in fp64. One wave per (b,g,h).
__global__ __launch_bounds__(64) void ikeys_f64_kernel(
    const float* __restrict__ x, const float* __restrict__ Wik,
    const float* __restrict__ Wig, const float* __restrict__ ape_i,
    double* __restrict__ ikeys64)
{
    int bid = blockIdx.x;              // (b*512+g)*8+h
    int h = bid & 7;
    int g = (bid >> 3) & (kG - 1);
    int b = bid >> 12;
    int lane = threadIdx.x;            // d
    __shared__ float xs[kRATIO][kC];
    const float* xp = x + (size_t)(b * kT + g * kRATIO) * kC;
    #pragma unroll
    for (int r = 0; r < kRATIO; ++r)
        #pragma unroll
        for (int i = 0; i < 4; ++i)
            *(float4*)&xs[r][lane * 4 + i * 256] =
                *(const float4*)&xp[(size_t)r * kC + lane * 4 + i * 256];
    __syncthreads();
    const float* wkp = Wik + h * kDI + lane;
    const float* wgp = Wig + h * kDI + lane;
    double kk[kRATIO] = {}, gg[kRATIO] = {};
    for (int c = 0; c < kC; ++c) {
        double wk = (double)wkp[(size_t)c * 512];
        double wg = (double)wgp[(size_t)c * 512];
        #pragma unroll
        for (int r = 0; r < kRATIO; ++r) {
            double xv = (double)xs[r][c];
            kk[r] += xv * wk;
            gg[r] += xv * wg;
        }
    }
    #pragma unroll
    for (int r = 0; r < kRATIO; ++r)
        gg[r] += (double)ape_i[(r * kHI + h) * kDI + lane];
    double m = fmax(fmax(gg[0], gg[1]), fmax(gg[2], gg[3]));
    double acc = 0.0, den = 0.0;
    #pragma unroll
    for (int r = 0; r < kRATIO; ++r) {
        double e = exp(gg[r] - m);
        den += e;
        acc += kk[r] * e;
    }
    acc /= den;
    double ss = waveReduceSumD(acc * acc);
    double scale = 1.0 / sqrt(ss * (1.0 / kDI) + 1e-6);
    ikeys64[((size_t)(b * kG + g) * kHI + h) * kDI + lane] = acc * scale;
}

// isc64 = (iq64 @ ikeys64^T) / 64, per batch. Tile 64x64, K=512, fp64 acc.
__global__ __launch_bounds__(256) void isc_f64_kernel(
    const double* __restrict__ iq64, const double* __restrict__ ikeys64,
    double* __restrict__ isc64)
{
    __shared__ double As[BK][BM + 1];
    __shared__ double Bs[BK][BN + 4];
    const int tid = threadIdx.x;
    const int bx = blockIdx.x, by = blockIdx.y;
    const int b = by >> 5;             // 32 row-tiles of 64 per batch
    const int tx = tid & 15, ty = tid >> 4;
    const int arow = tid >> 2;
    const int akq  = (tid & 3) << 2;
    const double* Ap = iq64 + (size_t)(by * BM + arow) * 512 + akq;
    const double* Bp = ikeys64 + (size_t)b * kG * 512 + (size_t)(bx * BN + arow) * 512 + akq;
    double acc[4][4] = {};
    for (int k0 = 0; k0 < 512; k0 += BK) {
        double a0 = Ap[k0], a1 = Ap[k0 + 1], a2 = Ap[k0 + 2], a3 = Ap[k0 + 3];
        double b0 = Bp[k0], b1 = Bp[k0 + 1], b2 = Bp[k0 + 2], b3 = Bp[k0 + 3];
        __syncthreads();
        As[akq + 0][arow] = a0; As[akq + 1][arow] = a1;
        As[akq + 2][arow] = a2; As[akq + 3][arow] = a3;
        Bs[akq + 0][arow] = b0; Bs[akq + 1][arow] = b1;
        Bs[akq + 2][arow] = b2; Bs[akq + 3][arow] = b3;
        __syncthreads();
        #pragma unroll
        for (int kk = 0; kk < BK; ++kk) {
            double a[4];
            #pragma unroll
            for (int i = 0; i < 4; ++i) a[i] = As[kk][ty * 4 + i];
            #pragma unroll
            for (int j = 0; j < 4; ++j) {
                double bv = Bs[kk][tx * 4 + j];
                #pragma unroll
                for (int i = 0; i < 4; ++i)
                    acc[i][j] = fma(a[i], bv, acc[i][j]);
            }
        }
    }
    #pragma unroll
    for (int i = 0; i < 4; ++i)
        #pragma unroll
        for (int j = 0; j < 4; ++j)
            isc64[(size_t)(by * BM + ty * 4 + i) * kG + bx * BN + tx * 4 + j] =
                acc[i][j] * (1.0 / 64.0);
}

// ---------------------------------------------------------------------------
// Top-k: exact jax.lax.top_k semantics via bitonic sort on composite key
// (value desc, index asc) over fp64 scores. One block(256) per (b,t).
// ---------------------------------------------------------------------------
__global__ __launch_bounds__(256) void topk_kernel(
    const double* __restrict__ isc, int* __restrict__ sel, int* __restrict__ cnt)
{
    int bt = blockIdx.x;
    int t = bt & (kT - 1);
    int tid = threadIdx.x;
    __shared__ double sv[kG];
    __shared__ int si[kG];
    const double* row = isc + (size_t)bt * kG;
    for (int g = tid; g < kG; g += 256) {
        bool causal = (4 * g + 3) <= t;
        sv[g] = causal ? row[g] : (double)kNEG;
        si[g] = g;
    }
    __syncthreads();
    for (int k = 2; k <= kG; k <<= 1) {
        for (int j = k >> 1; j > 0; j >>= 1) {
            for (int i = tid; i < kG; i += 256) {
                int l = i ^ j;
                if (l > i) {
                    double vi = sv[i], vl = sv[l];
                    int ii = si[i], il = si[l];
                    bool l_first = (vl > vi) || (vl == vi && il < ii);
                    bool desc = ((i & k) == 0);
                    if (desc ? l_first : !l_first) {
                        sv[i] = vl; sv[l] = vi;
                        si[i] = il; si[l] = ii;
                    }
                }
            }
            __syncthreads();
        }
    }
    int count = (t >= 3) ? (((t - 3) >> 2) + 1) : 0;
    int n = count < kTOPK ? count : kTOPK;
    if (tid < kTOPK) sel[(size_t)bt * kTOPK + tid] = (tid < n) ? si[tid] : 0;
    if (tid == 0) cnt[bt] = n;
}

// ---------------------------------------------------------------------------
// Sparse gathered attention: one wave per (b,t,h).
// ---------------------------------------------------------------------------
__global__ __launch_bounds__(64) void attn_kernel(
    const float* __restrict__ Y, const float* __restrict__ ck,
    const float* __restrict__ cv, const int* __restrict__ sel,
    const int* __restrict__ cnt, float* __restrict__ attn)
{
    int bid = blockIdx.x;
    int h = bid & 7;
    int row = bid >> 3;
    int b = row >> 11;
    int lane = threadIdx.x;
    __shared__ float qs[kD];
    __shared__ float ws[kTOPK];
    __shared__ int gs[kTOPK];
    const float* qp = Y + (size_t)row * NTOT + Q_OFF + h * kD;
    qs[lane] = qp[lane];
    qs[lane + 64] = qp[lane + 64];
    __syncthreads();
    int n = cnt[row];
    float* outp = attn + (size_t)row * kC + h * kD;
    if (n == 0) { outp[lane] = 0.f; outp[lane + 64] = 0.f; return; }
    int kvh = h >> 1;
    float score = kNEG;
    int g = 0;
    if (lane < n) {
        g = sel[(size_t)row * kTOPK + lane];
        const float* ckp = ck + ((size_t)(b * kG + g) * kHKV + kvh) * kD;
        float s = 0.f;
        #pragma unroll
        for (int d = 0; d < kD; d += 4) {
            float4 c4 = *(const float4*)(ckp + d);
            s += qs[d] * c4.x + qs[d + 1] * c4.y + qs[d + 2] * c4.z + qs[d + 3] * c4.w;
        }
        score = s * 0.08838834764831845f;
    }
    float m = waveReduceMax(score);
    float p = (lane < n) ? expf(score - m) : 0.f;
    float sum = waveReduceSum(p);
    float w = p / sum;
    ws[lane] = w;
    gs[lane] = g;
    __syncthreads();
    float acc0 = 0.f, acc1 = 0.f;
    for (int j = 0; j < n; ++j) {
        float wj = ws[j];
        const float* cvp = cv + ((size_t)(b * kG + gs[j]) * kHKV + kvh) * kD;
        acc0 = fmaf(wj, cvp[lane], acc0);
        acc1 = fmaf(wj, cvp[lane + 64], acc1);
    }
    outp[lane] = acc0;
    outp[lane + 64] = acc1;
}

// Row rms scales for r (RANK=512 per row). One wave per row.
__global__ __launch_bounds__(64) void rms_rows_kernel(
    const float* __restrict__ R, float* __restrict__ scale)
{
    int row = blockIdx.x;
    int lane = threadIdx.x;
    const float* p = R + (size_t)row * kRANK;
    float s = 0.f;
    #pragma unroll
    for (int i = 0; i < kRANK / 64; ++i) {
        float v = p[lane + i * 64];
        s = fmaf(v, v, s);
    }
    s = waveReduceSum(s);
    if (lane == 0) scale[row] = 1.0f / sqrtf(s * (1.0f / kRANK) + 1e-6f);
}

// ---------------------------------------------------------------------------
extern "C" void kernel_launch(void* const* d_in, const int* in_sizes, int n_in,
                              void* d_out, int out_size, void* d_ws, size_t ws_size,
                              hipStream_t stream)
{
    const float* x    = (const float*)d_in[0];
    const float* Wq   = (const float*)d_in[1];
    const float* Wck  = (const float*)d_in[2];
    const float* Wcv  = (const float*)d_in[3];
    const float* Wcg  = (const float*)d_in[4];
    const float* ape_c= (const float*)d_in[5];
    const float* Wiq  = (const float*)d_in[6];
    const float* Wik  = (const float*)d_in[7];
    const float* Wig  = (const float*)d_in[8];
    const float* ape_i= (const float*)d_in[9];
    const float* Wa   = (const float*)d_in[10];
    const float* Wb   = (const float*)d_in[11];
    float* out = (float*)d_out;

    const int M = kB * kT;  // 8192

    // Workspace carve
    float* Y       = (float*)d_ws;                             // 8192*2560 f32 (80 MiB)
    double* iq64   = (double*)(Y + (size_t)M * NTOT);          // 8192*512 f64 (32 MiB)
    double* ikeys64= iq64 + (size_t)M * 512;                   // 4*512*512 f64 (8 MiB)
    double* isc64  = ikeys64 + (size_t)kB * kG * 512;          // 8192*512 f64 (32 MiB)
    float* ck      = (float*)(isc64 + (size_t)M * kG);         // 4 MiB
    float* cv      = ck + (size_t)kB * kG * kHKV * kD;         // 4 MiB
    float* attnb   = cv + (size_t)kB * kG * kHKV * kD;         // 32 MiB
    float* rbuf    = attnb + (size_t)M * kC;                   // 16 MiB
    float* rscale  = rbuf + (size_t)M * kRANK;                 // 32 KiB
    int* sel       = (int*)(rscale + M);                       // 2 MiB
    int* cnt       = sel + (size_t)M * kTOPK;                  // 32 KiB

    // 1. Value-path projections: Y[:, slice] = x @ W
    gemm_nn_kernel<<<dim3(kH * kD / BN, M / BM), 256, 0, stream>>>(
        x, kC, Wq, kH * kD, Y + Q_OFF, NTOT, kC, 1.0f, nullptr);
    gemm_nn_kernel<<<dim3(512 / BN, M / BM), 256, 0, stream>>>(
        x, kC, Wck, 512, Y + CK_OFF, NTOT, kC, 1.0f, nullptr);
    gemm_nn_kernel<<<dim3(512 / BN, M / BM), 256, 0, stream>>>(
        x, kC, Wcv, 512, Y + CV_OFF, NTOT, kC, 1.0f, nullptr);
    gemm_nn_kernel<<<dim3(512 / BN, M / BM), 256, 0, stream>>>(
        x, kC, Wcg, 512, Y + CG_OFF, NTOT, kC, 1.0f, nullptr);

    // 2. RoPE on q; gated compress of ck/cv (+RoPE on ck)
    rope_q_kernel<<<(kB * kT * kH * 32) / 256, 256, 0, stream>>>(Y);
    compress_c_kernel<<<kB * kG * kHKV, 128, 0, stream>>>(Y, ape_c, ck, cv);

    // 3. fp64 indexer chain
    iq_f64_kernel<<<M * kHI, 64, 0, stream>>>(x, Wiq, iq64);
    ikeys_f64_kernel<<<kB * kG * kHI, 64, 0, stream>>>(x, Wik, Wig, ape_i, ikeys64);
    isc_f64_kernel<<<dim3(kG / BN, M / BM), 256, 0, stream>>>(iq64, ikeys64, isc64);

    // 4. Top-k selection (fp64 keys, exact jax tie semantics)
    topk_kernel<<<kB * kT, 256, 0, stream>>>(isc64, sel, cnt);

    // 5. Sparse attention
    attn_kernel<<<kB * kT * kH, 64, 0, stream>>>(Y, ck, cv, sel, cnt, attnb);

    // 6. r = attn @ Wa[0]^T
    gemm_nt_kernel<<<dim3(kRANK / BN, M / BM), 256, 0, stream>>>(
        attnb, kC, Wa, kC, rbuf, kRANK, kC, 1.0f);

    // 7. rmsnorm row scales, then out = (r*scale) @ Wb
    rms_rows_kernel<<<M, 64, 0, stream>>>(rbuf, rscale);
    gemm_nn_kernel<<<dim3(kC / BN, M / BM), 256, 0, stream>>>(
        rbuf, kRANK, Wb, kC, out, kC, 512, 1.0f, rscale);

    (void)in_sizes; (void)n_in; (void)out_size; (void)ws_size;
}

// Round 3
// 2338.168 us; speedup vs baseline: 1.2555x; 1.2555x over previous
//
#include <hip/hip_runtime.h>
#include <hip/hip_bf16.h>
#include <math.h>

// Problem constants
constexpr int kB = 4, kT = 2048, kC = 1024;
constexpr int kH = 8, kHKV = 4, kD = 128;
constexpr int kRATIO = 4, kG = 512;
constexpr int kHI = 8, kDI = 64;
constexpr int kTOPK = 64, kRANK = 512;
constexpr float kTHETA = 160000.0f;
constexpr float kNEG = -1e30f;

// Projection buffer column layout (value path; indexer path is fp64)
constexpr int NTOT = 2560;
constexpr int Q_OFF = 0;      // 1024 cols (H*D)
constexpr int CK_OFF = 1024;  // 512
constexpr int CV_OFF = 1536;  // 512
constexpr int CG_OFF = 2048;  // 512

typedef short short8 __attribute__((ext_vector_type(8)));
typedef float floatx4 __attribute__((ext_vector_type(4)));

__device__ inline float waveReduceSum(float v) {
    #pragma unroll
    for (int m = 32; m > 0; m >>= 1) v += __shfl_xor(v, m, 64);
    return v;
}
__device__ inline double waveReduceSumD(double v) {
    #pragma unroll
    for (int m = 32; m > 0; m >>= 1) v += __shfl_xor(v, m, 64);
    return v;
}
__device__ inline float waveReduceMax(float v) {
    #pragma unroll
    for (int m = 32; m > 0; m >>= 1) v = fmaxf(v, __shfl_xor(v, m, 64));
    return v;
}

// bf16 round-to-nearest-even (values are finite/well-behaved; no NaN path)
__device__ inline unsigned short f2bf(float f) {
    union { float f; unsigned int u; } v; v.f = f;
    unsigned int r = v.u + 0x7FFFu + ((v.u >> 16) & 1u);
    return (unsigned short)(r >> 16);
}
__device__ inline float bf2f(unsigned short h) {
    union { unsigned int u; float f; } v; v.u = ((unsigned int)h) << 16;
    return v.f;
}

// ---------------------------------------------------------------------------
// split_rows: in (rows x K fp32, optional per-row scale) -> out (rows x 2K bf16)
// out[row][0:K] = hi, out[row][K:2K] = lo.  One thread per 4 floats.
// kshift = log2(K/4).
// ---------------------------------------------------------------------------
__global__ __launch_bounds__(256) void split_rows_kernel(
    const float* __restrict__ in, unsigned short* __restrict__ out,
    int K, int kshift, const float* __restrict__ rowScale)
{
    int idx = blockIdx.x * 256 + threadIdx.x;
    int row = idx >> kshift;
    int kc = (idx & ((1 << kshift) - 1)) << 2;
    float4 v = *(const float4*)(in + (size_t)row * K + kc);
    if (rowScale) {
        float s = rowScale[row];
        v.x *= s; v.y *= s; v.z *= s; v.w *= s;
    }
    unsigned short h[4], l[4];
    float vv[4] = {v.x, v.y, v.z, v.w};
    #pragma unroll
    for (int i = 0; i < 4; ++i) {
        h[i] = f2bf(vv[i]);
        l[i] = f2bf(vv[i] - bf2f(h[i]));
    }
    size_t ob = (size_t)row * (2 * K);
    uint2 hw, lw;
    hw.x = (unsigned)h[0] | ((unsigned)h[1] << 16);
    hw.y = (unsigned)h[2] | ((unsigned)h[3] << 16);
    lw.x = (unsigned)l[0] | ((unsigned)l[1] << 16);
    lw.y = (unsigned)l[2] | ((unsigned)l[3] << 16);
    *(uint2*)(out + ob + kc) = hw;
    *(uint2*)(out + ob + K + kc) = lw;
}

// ---------------------------------------------------------------------------
// transpose_split: W (K x N fp32, row-major) -> Wt (N x 2K bf16):
// Wt[n][0:K] = hi(W[:,n]), Wt[n][K:2K] = lo. 64x64 tiles via LDS.
// ---------------------------------------------------------------------------
__global__ __launch_bounds__(256) void transpose_split_kernel(
    const float* __restrict__ W, int N, int K, unsigned short* __restrict__ Wt)
{
    __shared__ float Ws[64][68];
    int k0 = blockIdx.x * 64, n0 = blockIdx.y * 64;
    int tid = threadIdx.x;
    #pragma unroll
    for (int it = 0; it < 4; ++it) {
        int krow = (tid >> 4) + it * 16;
        float4 v = *(const float4*)(W + (size_t)(k0 + krow) * N + n0 + (tid & 15) * 4);
        *(float4*)&Ws[krow][(tid & 15) * 4] = v;
    }
    __syncthreads();
    #pragma unroll
    for (int it = 0; it < 2; ++it) {
        int idx = tid + it * 256;          // 0..511
        int nrow = idx >> 3;
        int kc8 = (idx & 7) * 8;
        unsigned short h[8], l[8];
        #pragma unroll
        for (int j = 0; j < 8; ++j) {
            float v = Ws[kc8 + j][nrow];
            h[j] = f2bf(v);
            l[j] = f2bf(v - bf2f(h[j]));
        }
        size_t ob = (size_t)(n0 + nrow) * (2 * K) + k0;
        uint4 hw, lw;
        hw.x = (unsigned)h[0] | ((unsigned)h[1] << 16);
        hw.y = (unsigned)h[2] | ((unsigned)h[3] << 16);
        hw.z = (unsigned)h[4] | ((unsigned)h[5] << 16);
        hw.w = (unsigned)h[6] | ((unsigned)h[7] << 16);
        lw.x = (unsigned)l[0] | ((unsigned)l[1] << 16);
        lw.y = (unsigned)l[2] | ((unsigned)l[3] << 16);
        lw.z = (unsigned)l[4] | ((unsigned)l[5] << 16);
        lw.w = (unsigned)l[6] | ((unsigned)l[7] << 16);
        *(uint4*)(Wt + ob + kc8) = hw;
        *(uint4*)(Wt + ob + K + kc8) = lw;
    }
}

// ---------------------------------------------------------------------------
// Split-bf16 MFMA GEMM: C(MxN f32) = A * B^T using bf16 16x16x32 MFMA.
// A: M x 2*Kin bf16 [hi|lo]; B: N x 2*Kin bf16 [hi|lo] (pre-transposed).
// Iterates K' = 3*Kin: blocks [A_hi*B_hi, A_lo*B_hi, A_hi*B_lo] -> fp32-grade.
// 128x128 tile, 256 threads (4 waves, each 64x64 = 4x4 MFMA tiles).
// ---------------------------------------------------------------------------
#define TSTRIDE 40  // 32 bf16 + 8 pad: ds_read_b128 2-way conflict only (free)

__global__ __launch_bounds__(256) void gemm_mfma_kernel(
    const unsigned short* __restrict__ A,
    const unsigned short* __restrict__ B,
    float* __restrict__ C, int ldc, int Kin)
{
    __shared__ unsigned short As[128 * TSTRIDE];
    __shared__ unsigned short Bs[128 * TSTRIDE];
    const int tid = threadIdx.x;
    const int n0 = blockIdx.x * 128, m0 = blockIdx.y * 128;
    const int w = tid >> 6, lane = tid & 63;
    const int q = lane >> 4, r = lane & 15;
    const int wm = (w & 1) * 64, wn = (w >> 1) * 64;
    const int lda = 2 * Kin, ldb = 2 * Kin;
    const int srow = tid >> 2;              // 0..63 (stage row base, 2 reps)
    const int sko = (tid & 3) * 8;          // 0,8,16,24

    floatx4 acc[4][4] = {};
    const int KT = 3 * Kin;
    for (int k0 = 0; k0 < KT; k0 += 32) {
        int ka = (k0 < 2 * Kin) ? k0 : k0 - 2 * Kin;
        int kb = (k0 < Kin) ? k0 : k0 - Kin;
        __syncthreads();
        #pragma unroll
        for (int rep = 0; rep < 2; ++rep) {
            int row = srow + rep * 64;
            uint4 av = *(const uint4*)(A + (size_t)(m0 + row) * lda + ka + sko);
            uint4 bv = *(const uint4*)(B + (size_t)(n0 + row) * ldb + kb + sko);
            *(uint4*)&As[row * TSTRIDE + sko] = av;
            *(uint4*)&Bs[row * TSTRIDE + sko] = bv;
        }
        __syncthreads();
        short8 af[4], bf[4];
        #pragma unroll
        for (int i = 0; i < 4; ++i)
            af[i] = *(const short8*)&As[(wm + i * 16 + r) * TSTRIDE + q * 8];
        #pragma unroll
        for (int j = 0; j < 4; ++j)
            bf[j] = *(const short8*)&Bs[(wn + j * 16 + r) * TSTRIDE + q * 8];
        #pragma unroll
        for (int i = 0; i < 4; ++i)
            #pragma unroll
            for (int j = 0; j < 4; ++j)
                acc[i][j] = __builtin_amdgcn_mfma_f32_16x16x32_bf16(
                    af[i], bf[j], acc[i][j], 0, 0, 0);
    }
    // C/D layout: col = lane&15 (n), row = q*4 + reg (m)
    #pragma unroll
    for (int i = 0; i < 4; ++i)
        #pragma unroll
        for (int j = 0; j < 4; ++j)
            #pragma unroll
            for (int reg = 0; reg < 4; ++reg)
                C[(size_t)(m0 + wm + i * 16 + q * 4 + reg) * ldc
                  + n0 + wn + j * 16 + r] = acc[i][j][reg];
}

// ---------------------------------------------------------------------------
// In-place partial RoPE on the q columns of Y. One thread per (b,t,h,j<32).
// ---------------------------------------------------------------------------
__global__ __launch_bounds__(256) void rope_q_kernel(float* __restrict__ Y)
{
    int idx = blockIdx.x * 256 + threadIdx.x;
    int j = idx & 31;
    int rest = idx >> 5;
    int h = rest & 7;  rest >>= 3;
    int t = rest & (kT - 1);
    int b = rest >> 11;
    size_t base = (size_t)(b * kT + t) * NTOT + Q_OFF + h * kD;
    float inv_freq = powf(kTHETA, -(float)j * (1.0f / 32.0f));
    float ang = (float)t * inv_freq;
    float c = cosf(ang), s = sinf(ang);
    float x1 = Y[base + 64 + j];
    float x2 = Y[base + 96 + j];
    Y[base + 64 + j] = x1 * c - x2 * s;
    Y[base + 96 + j] = x1 * s + x2 * c;
}

// Gated compress for main KV + RoPE on ck. One block(128) per (b,g,h in HKV).
__global__ __launch_bounds__(128) void compress_c_kernel(
    const float* __restrict__ Y, const float* __restrict__ ape_c,
    float* __restrict__ ck, float* __restrict__ cv)
{
    int bid = blockIdx.x;
    int h = bid & 3;
    int g = (bid >> 2) & (kG - 1);
    int b = bid >> 11;
    int d = threadIdx.x;
    float kv[kRATIO], vv[kRATIO], gv[kRATIO];
    #pragma unroll
    for (int r = 0; r < kRATIO; ++r) {
        size_t row = (size_t)(b * kT + g * kRATIO + r) * NTOT;
        kv[r] = Y[row + CK_OFF + h * kD + d];
        vv[r] = Y[row + CV_OFF + h * kD + d];
        gv[r] = Y[row + CG_OFF + h * kD + d] + ape_c[(r * kHKV + h) * kD + d];
    }
    float m = fmaxf(fmaxf(gv[0], gv[1]), fmaxf(gv[2], gv[3]));
    float ka = 0.f, va = 0.f, den = 0.f;
    #pragma unroll
    for (int r = 0; r < kRATIO; ++r) {
        float e = expf(gv[r] - m);
        den += e;
        ka += kv[r] * e;
        va += vv[r] * e;
    }
    ka /= den; va /= den;
    size_t obase = ((size_t)(b * kG + g) * kHKV + h) * kD;
    cv[obase + d] = va;
    __shared__ float cks[kD];
    cks[d] = ka;
    __syncthreads();
    int pos = 4 * g + 3;
    float out;
    if (d < 64) {
        out = cks[d];
    } else if (d < 96) {
        int j = d - 64;
        float inv_freq = powf(kTHETA, -(float)j * (1.0f / 32.0f));
        float ang = (float)pos * inv_freq;
        out = cks[d] * cosf(ang) - cks[d + 32] * sinf(ang);
    } else {
        int j = d - 96;
        float inv_freq = powf(kTHETA, -(float)j * (1.0f / 32.0f));
        float ang = (float)pos * inv_freq;
        out = cks[d - 32] * sinf(ang) + cks[d] * cosf(ang);
    }
    ck[obase + d] = out;
}

// ---------------------------------------------------------------------------
// fp64 indexer chain (selection is a discontinuous argmax — needs ~1e-9
// accuracy so ordering matches the fp32 numpy reference's boundary gaps).
// ---------------------------------------------------------------------------
__global__ __launch_bounds__(64) void iq_f64_kernel(
    const float* __restrict__ x, const float* __restrict__ Wiq,
    double* __restrict__ iq64)
{
    int bid = blockIdx.x;              // row*8 + h
    int h = bid & 7;
    int row = bid >> 3;
    int lane = threadIdx.x;
    __shared__ float xs[kC];
    const float* xp = x + (size_t)row * kC;
    #pragma unroll
    for (int i = 0; i < 4; ++i)
        *(float4*)&xs[lane * 4 + i * 256] = *(const float4*)&xp[lane * 4 + i * 256];
    __syncthreads();
    const float* wp = Wiq + h * kDI + lane;
    double acc = 0.0;
    for (int c = 0; c < kC; ++c)
        acc += (double)xs[c] * (double)wp[(size_t)c * 512];
    double ss = waveReduceSumD(acc * acc);
    double scale = 1.0 / sqrt(ss * (1.0 / kDI) + 1e-6);
    iq64[(size_t)row * 512 + h * kDI + lane] = acc * scale;
}

__global__ __launch_bounds__(64) void ikeys_f64_kernel(
    const float* __restrict__ x, const float* __restrict__ Wik,
    const float* __restrict__ Wig, const float* __restrict__ ape_i,
    double* __restrict__ ikeys64)
{
    int bid = blockIdx.x;              // (b*512+g)*8+h
    int h = bid & 7;
    int g = (bid >> 3) & (kG - 1);
    int b = bid >> 12;
    int lane = threadIdx.x;            // d
    __shared__ float xs[kRATIO][kC];
    const float* xp = x + (size_t)(b * kT + g * kRATIO) * kC;
    #pragma unroll
    for (int r = 0; r < kRATIO; ++r)
        #pragma unroll
        for (int i = 0; i < 4; ++i)
            *(float4*)&xs[r][lane * 4 + i * 256] =
                *(const float4*)&xp[(size_t)r * kC + lane * 4 + i * 256];
    __syncthreads();
    const float* wkp = Wik + h * kDI + lane;
    const float* wgp = Wig + h * kDI + lane;
    double kk[kRATIO] = {}, gg[kRATIO] = {};
    for (int c = 0; c < kC; ++c) {
        double wk = (double)wkp[(size_t)c * 512];
        double wg = (double)wgp[(size_t)c * 512];
        #pragma unroll
        for (int r = 0; r < kRATIO; ++r) {
            double xv = (double)xs[r][c];
            kk[r] += xv * wk;
            gg[r] += xv * wg;
        }
    }
    #pragma unroll
    for (int r = 0; r < kRATIO; ++r)
        gg[r] += (double)ape_i[(r * kHI + h) * kDI + lane];
    double m = fmax(fmax(gg[0], gg[1]), fmax(gg[2], gg[3]));
    double acc = 0.0, den = 0.0;
    #pragma unroll
    for (int r = 0; r < kRATIO; ++r) {
        double e = exp(gg[r] - m);
        den += e;
        acc += kk[r] * e;
    }
    acc /= den;
    double ss = waveReduceSumD(acc * acc);
    double scale = 1.0 / sqrt(ss * (1.0 / kDI) + 1e-6);
    ikeys64[((size_t)(b * kG + g) * kHI + h) * kDI + lane] = acc * scale;
}

#define BM 64
#define BN 64
#define BK 16

// isc64 = (iq64 @ ikeys64^T) / 64, per batch. Tile 64x64, K=512, fp64 acc.
__global__ __launch_bounds__(256) void isc_f64_kernel(
    const double* __restrict__ iq64, const double* __restrict__ ikeys64,
    double* __restrict__ isc64)
{
    __shared__ double As[BK][BM + 1];
    __shared__ double Bs[BK][BN + 4];
    const int tid = threadIdx.x;
    const int bx = blockIdx.x, by = blockIdx.y;
    const int b = by >> 5;
    const int tx = tid & 15, ty = tid >> 4;
    const int arow = tid >> 2;
    const int akq  = (tid & 3) << 2;
    const double* Ap = iq64 + (size_t)(by * BM + arow) * 512 + akq;
    const double* Bp = ikeys64 + (size_t)b * kG * 512 + (size_t)(bx * BN + arow) * 512 + akq;
    double acc[4][4] = {};
    for (int k0 = 0; k0 < 512; k0 += BK) {
        double a0 = Ap[k0], a1 = Ap[k0 + 1], a2 = Ap[k0 + 2], a3 = Ap[k0 + 3];
        double b0 = Bp[k0], b1 = Bp[k0 + 1], b2 = Bp[k0 + 2], b3 = Bp[k0 + 3];
        __syncthreads();
        As[akq + 0][arow] = a0; As[akq + 1][arow] = a1;
        As[akq + 2][arow] = a2; As[akq + 3][arow] = a3;
        Bs[akq + 0][arow] = b0; Bs[akq + 1][arow] = b1;
        Bs[akq + 2][arow] = b2; Bs[akq + 3][arow] = b3;
        __syncthreads();
        #pragma unroll
        for (int kk = 0; kk < BK; ++kk) {
            double a[4];
            #pragma unroll
            for (int i = 0; i < 4; ++i) a[i] = As[kk][ty * 4 + i];
            #pragma unroll
            for (int j = 0; j < 4; ++j) {
                double bv = Bs[kk][tx * 4 + j];
                #pragma unroll
                for (int i = 0; i < 4; ++i)
                    acc[i][j] = fma(a[i], bv, acc[i][j]);
            }
        }
    }
    #pragma unroll
    for (int i = 0; i < 4; ++i)
        #pragma unroll
        for (int j = 0; j < 4; ++j)
            isc64[(size_t)(by * BM + ty * 4 + i) * kG + bx * BN + tx * 4 + j] =
                acc[i][j] * (1.0 / 64.0);
}

// ---------------------------------------------------------------------------
// Top-k: exact jax.lax.top_k semantics via bitonic sort (value desc, idx asc).
// ---------------------------------------------------------------------------
__global__ __launch_bounds__(256) void topk_kernel(
    const double* __restrict__ isc, int* __restrict__ sel, int* __restrict__ cnt)
{
    int bt = blockIdx.x;
    int t = bt & (kT - 1);
    int tid = threadIdx.x;
    __shared__ double sv[kG];
    __shared__ int si[kG];
    const double* row = isc + (size_t)bt * kG;
    for (int g = tid; g < kG; g += 256) {
        bool causal = (4 * g + 3) <= t;
        sv[g] = causal ? row[g] : (double)kNEG;
        si[g] = g;
    }
    __syncthreads();
    for (int k = 2; k <= kG; k <<= 1) {
        for (int j = k >> 1; j > 0; j >>= 1) {
            for (int i = tid; i < kG; i += 256) {
                int l = i ^ j;
                if (l > i) {
                    double vi = sv[i], vl = sv[l];
                    int ii = si[i], il = si[l];
                    bool l_first = (vl > vi) || (vl == vi && il < ii);
                    bool desc = ((i & k) == 0);
                    if (desc ? l_first : !l_first) {
                        sv[i] = vl; sv[l] = vi;
                        si[i] = il; si[l] = ii;
                    }
                }
            }
            __syncthreads();
        }
    }
    int count = (t >= 3) ? (((t - 3) >> 2) + 1) : 0;
    int n = count < kTOPK ? count : kTOPK;
    if (tid < kTOPK) sel[(size_t)bt * kTOPK + tid] = (tid < n) ? si[tid] : 0;
    if (tid == 0) cnt[bt] = n;
}

// ---------------------------------------------------------------------------
// Sparse gathered attention: one wave per (b,t,h). Writes output directly as
// split bf16 [hi|lo] rows (feeds the Wa MFMA GEMM).
// ---------------------------------------------------------------------------
__global__ __launch_bounds__(64) void attn_kernel(
    const float* __restrict__ Y, const float* __restrict__ ck,
    const float* __restrict__ cv, const int* __restrict__ sel,
    const int* __restrict__ cnt, unsigned short* __restrict__ acat)
{
    int bid = blockIdx.x;
    int h = bid & 7;
    int row = bid >> 3;
    int b = row >> 11;
    int lane = threadIdx.x;
    __shared__ float qs[kD];
    __shared__ float ws[kTOPK];
    __shared__ int gs[kTOPK];
    const float* qp = Y + (size_t)row * NTOT + Q_OFF + h * kD;
    qs[lane] = qp[lane];
    qs[lane + 64] = qp[lane + 64];
    __syncthreads();
    int n = cnt[row];
    unsigned short* outp = acat + (size_t)row * 2048 + h * kD;  // [hi|lo], K=1024
    float acc0 = 0.f, acc1 = 0.f;
    if (n > 0) {
        int kvh = h >> 1;
        float score = kNEG;
        int g = 0;
        if (lane < n) {
            g = sel[(size_t)row * kTOPK + lane];
            const float* ckp = ck + ((size_t)(b * kG + g) * kHKV + kvh) * kD;
            float s = 0.f;
            #pragma unroll
            for (int d = 0; d < kD; d += 4) {
                float4 c4 = *(const float4*)(ckp + d);
                s += qs[d] * c4.x + qs[d + 1] * c4.y + qs[d + 2] * c4.z + qs[d + 3] * c4.w;
            }
            score = s * 0.08838834764831845f;
        }
        float m = waveReduceMax(score);
        float p = (lane < n) ? expf(score - m) : 0.f;
        float sum = waveReduceSum(p);
        float w = p / sum;
        ws[lane] = w;
        gs[lane] = g;
        __syncthreads();
        for (int j = 0; j < n; ++j) {
            float wj = ws[j];
            const float* cvp = cv + ((size_t)(b * kG + gs[j]) * kHKV + kvh) * kD;
            acc0 = fmaf(wj, cvp[lane], acc0);
            acc1 = fmaf(wj, cvp[lane + 64], acc1);
        }
    }
    unsigned short h0 = f2bf(acc0), h1 = f2bf(acc1);
    outp[lane] = h0;
    outp[lane + 64] = h1;
    outp[1024 + lane] = f2bf(acc0 - bf2f(h0));
    outp[1024 + lane + 64] = f2bf(acc1 - bf2f(h1));
}

// Row rms scales for r (RANK=512 per row). One wave per row.
__global__ __launch_bounds__(64) void rms_rows_kernel(
    const float* __restrict__ R, float* __restrict__ scale)
{
    int row = blockIdx.x;
    int lane = threadIdx.x;
    const float* p = R + (size_t)row * kRANK;
    float s = 0.f;
    #pragma unroll
    for (int i = 0; i < kRANK / 64; ++i) {
        float v = p[lane + i * 64];
        s = fmaf(v, v, s);
    }
    s = waveReduceSum(s);
    if (lane == 0) scale[row] = 1.0f / sqrtf(s * (1.0f / kRANK) + 1e-6f);
}

// ---------------------------------------------------------------------------
extern "C" void kernel_launch(void* const* d_in, const int* in_sizes, int n_in,
                              void* d_out, int out_size, void* d_ws, size_t ws_size,
                              hipStream_t stream)
{
    const float* x    = (const float*)d_in[0];
    const float* Wq   = (const float*)d_in[1];
    const float* Wck  = (const float*)d_in[2];
    const float* Wcv  = (const float*)d_in[3];
    const float* Wcg  = (const float*)d_in[4];
    const float* ape_c= (const float*)d_in[5];
    const float* Wiq  = (const float*)d_in[6];
    const float* Wik  = (const float*)d_in[7];
    const float* Wig  = (const float*)d_in[8];
    const float* ape_i= (const float*)d_in[9];
    const float* Wa   = (const float*)d_in[10];
    const float* Wb   = (const float*)d_in[11];
    float* out = (float*)d_out;

    const int M = kB * kT;  // 8192

    // Workspace carve (bytes accounted; ~235 MB total with aliasing)
    char* p = (char*)d_ws;
    float* Y        = (float*)p;               p += (size_t)M * NTOT * 4;       // 83.9 MB
    double* iq64    = (double*)p;              p += (size_t)M * 512 * 8;        // 33.6 MB
    double* ikeys64 = (double*)p;              p += (size_t)kB * kG * 512 * 8;  //  8.4 MB
    double* isc64   = (double*)p;              p += (size_t)M * kG * 8;         // 33.6 MB
    float* ck       = (float*)p;               p += (size_t)kB * kG * kHKV * kD * 4;
    float* cv       = (float*)p;               p += (size_t)kB * kG * kHKV * kD * 4;
    float* rbuf     = (float*)p;               p += (size_t)M * kRANK * 4;      // 16.8 MB
    float* rscale   = (float*)p;               p += (size_t)M * 4;
    int* sel        = (int*)p;                 p += (size_t)M * kTOPK * 4;
    int* cnt        = (int*)p;                 p += (size_t)M * 4;
    unsigned short* xcat  = (unsigned short*)p; p += (size_t)M * 2048 * 2;      // 33.6 MB
    unsigned short* Wtall = (unsigned short*)p; p += (size_t)NTOT * 2048 * 2;   // 10.5 MB
    unsigned short* Wat   = (unsigned short*)p; p += (size_t)kRANK * 2048 * 2;  //  2.1 MB
    unsigned short* Wbt   = (unsigned short*)p; p += (size_t)kC * 1024 * 2;     //  2.1 MB
    // Aliases (lifetime-disjoint): acat over xcat (xcat dead after proj GEMM);
    // rncat over iq64 (iq64 dead after isc_f64).
    unsigned short* acat  = xcat;
    unsigned short* rncat = (unsigned short*)iq64;

    // 1. Split x -> [hi|lo] bf16; transpose+split weights -> Wtall (N x 2K)
    split_rows_kernel<<<(size_t)M * kC / 4 / 256, 256, 0, stream>>>(
        x, xcat, kC, 8, nullptr);
    transpose_split_kernel<<<dim3(kC / 64, 1024 / 64), 256, 0, stream>>>(
        Wq, 1024, kC, Wtall + (size_t)Q_OFF * 2048);
    transpose_split_kernel<<<dim3(kC / 64, 512 / 64), 256, 0, stream>>>(
        Wck, 512, kC, Wtall + (size_t)CK_OFF * 2048);
    transpose_split_kernel<<<dim3(kC / 64, 512 / 64), 256, 0, stream>>>(
        Wcv, 512, kC, Wtall + (size_t)CV_OFF * 2048);
    transpose_split_kernel<<<dim3(kC / 64, 512 / 64), 256, 0, stream>>>(
        Wcg, 512, kC, Wtall + (size_t)CG_OFF * 2048);

    // 2. Fused projection GEMM (MFMA, split-bf16 3-pass): Y = x @ [Wq|Wck|Wcv|Wcg]
    gemm_mfma_kernel<<<dim3(NTOT / 128, M / 128), 256, 0, stream>>>(
        xcat, Wtall, Y, NTOT, kC);

    // 3. RoPE on q; gated compress of ck/cv (+RoPE on ck)
    rope_q_kernel<<<(kB * kT * kH * 32) / 256, 256, 0, stream>>>(Y);
    compress_c_kernel<<<kB * kG * kHKV, 128, 0, stream>>>(Y, ape_c, ck, cv);

    // 4. fp64 indexer chain + top-k
    iq_f64_kernel<<<M * kHI, 64, 0, stream>>>(x, Wiq, iq64);
    ikeys_f64_kernel<<<kB * kG * kHI, 64, 0, stream>>>(x, Wik, Wig, ape_i, ikeys64);
    isc_f64_kernel<<<dim3(kG / BN, M / BM), 256, 0, stream>>>(iq64, ikeys64, isc64);
    topk_kernel<<<kB * kT, 256, 0, stream>>>(isc64, sel, cnt);

    // 5. Sparse attention -> acat (split bf16, aliases xcat)
    attn_kernel<<<kB * kT * kH, 64, 0, stream>>>(Y, ck, cv, sel, cnt, acat);

    // 6. r = attn @ Wa^T  (Wa is RANKxC row-major == already N x K; split only)
    split_rows_kernel<<<(size_t)kRANK * kC / 4 / 256, 256, 0, stream>>>(
        Wa, Wat, kC, 8, nullptr);
    gemm_mfma_kernel<<<dim3(kRANK / 128, M / 128), 256, 0, stream>>>(
        acat, Wat, rbuf, kRANK, kC);

    // 7. rmsnorm scales; split r*scale; out = rn @ Wb (MFMA)
    rms_rows_kernel<<<M, 64, 0, stream>>>(rbuf, rscale);
    split_rows_kernel<<<(size_t)M * kRANK / 4 / 256, 256, 0, stream>>>(
        rbuf, rncat, kRANK, 7, rscale);
    transpose_split_kernel<<<dim3(kRANK / 64, kC / 64), 256, 0, stream>>>(
        Wb, kC, kRANK, Wbt);
    gemm_mfma_kernel<<<dim3(kC / 128, M / 128), 256, 0, stream>>>(
        rncat, Wbt, out, kC, kRANK);

    (void)in_sizes; (void)n_in; (void)out_size; (void)ws_size;
}

// Round 4
// 1795.406 us; speedup vs baseline: 1.6351x; 1.3023x over previous
//
#include <hip/hip_runtime.h>
#include <hip/hip_bf16.h>
#include <math.h>

// Problem constants
constexpr int kB = 4, kT = 2048, kC = 1024;
constexpr int kH = 8, kHKV = 4, kD = 128;
constexpr int kRATIO = 4, kG = 512;
constexpr int kHI = 8, kDI = 64;
constexpr int kTOPK = 64, kRANK = 512;
constexpr float kTHETA = 160000.0f;
constexpr float kNEG = -1e30f;

// Projection buffer column layout (value path; indexer path is fp64)
constexpr int NTOT = 2560;
constexpr int Q_OFF = 0;      // 1024 cols (H*D)
constexpr int CK_OFF = 1024;  // 512
constexpr int CV_OFF = 1536;  // 512
constexpr int CG_OFF = 2048;  // 512

// fp64 indexer projection buffer P: 8192 x 1536 (iq | ki | gi)
constexpr int PLD = 1536;
constexpr int P_IQ = 0, P_KI = 512, P_GI = 1024;

typedef short short8 __attribute__((ext_vector_type(8)));
typedef float floatx4 __attribute__((ext_vector_type(4)));

__device__ inline float waveReduceSum(float v) {
    #pragma unroll
    for (int m = 32; m > 0; m >>= 1) v += __shfl_xor(v, m, 64);
    return v;
}
__device__ inline double waveReduceSumD(double v) {
    #pragma unroll
    for (int m = 32; m > 0; m >>= 1) v += __shfl_xor(v, m, 64);
    return v;
}
__device__ inline float waveReduceMax(float v) {
    #pragma unroll
    for (int m = 32; m > 0; m >>= 1) v = fmaxf(v, __shfl_xor(v, m, 64));
    return v;
}

// bf16 round-to-nearest-even (values are finite/well-behaved; no NaN path)
__device__ inline unsigned short f2bf(float f) {
    union { float f; unsigned int u; } v; v.f = f;
    unsigned int r = v.u + 0x7FFFu + ((v.u >> 16) & 1u);
    return (unsigned short)(r >> 16);
}
__device__ inline float bf2f(unsigned short h) {
    union { unsigned int u; float f; } v; v.u = ((unsigned int)h) << 16;
    return v.f;
}

// ---------------------------------------------------------------------------
// split_rows: in (rows x K fp32, optional per-row scale) -> out (rows x 2K bf16)
// ---------------------------------------------------------------------------
__global__ __launch_bounds__(256) void split_rows_kernel(
    const float* __restrict__ in, unsigned short* __restrict__ out,
    int K, int kshift, const float* __restrict__ rowScale)
{
    int idx = blockIdx.x * 256 + threadIdx.x;
    int row = idx >> kshift;
    int kc = (idx & ((1 << kshift) - 1)) << 2;
    float4 v = *(const float4*)(in + (size_t)row * K + kc);
    if (rowScale) {
        float s = rowScale[row];
        v.x *= s; v.y *= s; v.z *= s; v.w *= s;
    }
    unsigned short h[4], l[4];
    float vv[4] = {v.x, v.y, v.z, v.w};
    #pragma unroll
    for (int i = 0; i < 4; ++i) {
        h[i] = f2bf(vv[i]);
        l[i] = f2bf(vv[i] - bf2f(h[i]));
    }
    size_t ob = (size_t)row * (2 * K);
    uint2 hw, lw;
    hw.x = (unsigned)h[0] | ((unsigned)h[1] << 16);
    hw.y = (unsigned)h[2] | ((unsigned)h[3] << 16);
    lw.x = (unsigned)l[0] | ((unsigned)l[1] << 16);
    lw.y = (unsigned)l[2] | ((unsigned)l[3] << 16);
    *(uint2*)(out + ob + kc) = hw;
    *(uint2*)(out + ob + K + kc) = lw;
}

// ---------------------------------------------------------------------------
// transpose_split: W (K x N fp32, row-major) -> Wt (N x 2K bf16) [hi|lo]
// ---------------------------------------------------------------------------
__global__ __launch_bounds__(256) void transpose_split_kernel(
    const float* __restrict__ W, int N, int K, unsigned short* __restrict__ Wt)
{
    __shared__ float Ws[64][68];
    int k0 = blockIdx.x * 64, n0 = blockIdx.y * 64;
    int tid = threadIdx.x;
    #pragma unroll
    for (int it = 0; it < 4; ++it) {
        int krow = (tid >> 4) + it * 16;
        float4 v = *(const float4*)(W + (size_t)(k0 + krow) * N + n0 + (tid & 15) * 4);
        *(float4*)&Ws[krow][(tid & 15) * 4] = v;
    }
    __syncthreads();
    #pragma unroll
    for (int it = 0; it < 2; ++it) {
        int idx = tid + it * 256;
        int nrow = idx >> 3;
        int kc8 = (idx & 7) * 8;
        unsigned short h[8], l[8];
        #pragma unroll
        for (int j = 0; j < 8; ++j) {
            float v = Ws[kc8 + j][nrow];
            h[j] = f2bf(v);
            l[j] = f2bf(v - bf2f(h[j]));
        }
        size_t ob = (size_t)(n0 + nrow) * (2 * K) + k0;
        uint4 hw, lw;
        hw.x = (unsigned)h[0] | ((unsigned)h[1] << 16);
        hw.y = (unsigned)h[2] | ((unsigned)h[3] << 16);
        hw.z = (unsigned)h[4] | ((unsigned)h[5] << 16);
        hw.w = (unsigned)h[6] | ((unsigned)h[7] << 16);
        lw.x = (unsigned)l[0] | ((unsigned)l[1] << 16);
        lw.y = (unsigned)l[2] | ((unsigned)l[3] << 16);
        lw.z = (unsigned)l[4] | ((unsigned)l[5] << 16);
        lw.w = (unsigned)l[6] | ((unsigned)l[7] << 16);
        *(uint4*)(Wt + ob + kc8) = hw;
        *(uint4*)(Wt + ob + K + kc8) = lw;
    }
}

// ---------------------------------------------------------------------------
// Split-bf16 MFMA GEMM: C(MxN f32) = A * B^T using bf16 16x16x32 MFMA.
// K' = 3*Kin passes: [A_hi*B_hi, A_lo*B_hi, A_hi*B_lo] -> fp32-grade.
// ---------------------------------------------------------------------------
#define TSTRIDE 40  // 32 bf16 + 8 pad

__global__ __launch_bounds__(256) void gemm_mfma_kernel(
    const unsigned short* __restrict__ A,
    const unsigned short* __restrict__ B,
    float* __restrict__ C, int ldc, int Kin)
{
    __shared__ unsigned short As[128 * TSTRIDE];
    __shared__ unsigned short Bs[128 * TSTRIDE];
    const int tid = threadIdx.x;
    const int n0 = blockIdx.x * 128, m0 = blockIdx.y * 128;
    const int w = tid >> 6, lane = tid & 63;
    const int q = lane >> 4, r = lane & 15;
    const int wm = (w & 1) * 64, wn = (w >> 1) * 64;
    const int lda = 2 * Kin, ldb = 2 * Kin;
    const int srow = tid >> 2;
    const int sko = (tid & 3) * 8;

    floatx4 acc[4][4] = {};
    const int KT = 3 * Kin;
    for (int k0 = 0; k0 < KT; k0 += 32) {
        int ka = (k0 < 2 * Kin) ? k0 : k0 - 2 * Kin;
        int kb = (k0 < Kin) ? k0 : k0 - Kin;
        __syncthreads();
        #pragma unroll
        for (int rep = 0; rep < 2; ++rep) {
            int row = srow + rep * 64;
            uint4 av = *(const uint4*)(A + (size_t)(m0 + row) * lda + ka + sko);
            uint4 bv = *(const uint4*)(B + (size_t)(n0 + row) * ldb + kb + sko);
            *(uint4*)&As[row * TSTRIDE + sko] = av;
            *(uint4*)&Bs[row * TSTRIDE + sko] = bv;
        }
        __syncthreads();
        short8 af[4], bf[4];
        #pragma unroll
        for (int i = 0; i < 4; ++i)
            af[i] = *(const short8*)&As[(wm + i * 16 + r) * TSTRIDE + q * 8];
        #pragma unroll
        for (int j = 0; j < 4; ++j)
            bf[j] = *(const short8*)&Bs[(wn + j * 16 + r) * TSTRIDE + q * 8];
        #pragma unroll
        for (int i = 0; i < 4; ++i)
            #pragma unroll
            for (int j = 0; j < 4; ++j)
                acc[i][j] = __builtin_amdgcn_mfma_f32_16x16x32_bf16(
                    af[i], bf[j], acc[i][j], 0, 0, 0);
    }
    #pragma unroll
    for (int i = 0; i < 4; ++i)
        #pragma unroll
        for (int j = 0; j < 4; ++j)
            #pragma unroll
            for (int reg = 0; reg < 4; ++reg)
                C[(size_t)(m0 + wm + i * 16 + q * 4 + reg) * ldc
                  + n0 + wn + j * 16 + r] = acc[i][j][reg];
}

// ---------------------------------------------------------------------------
// In-place partial RoPE on q columns of Y.
// ---------------------------------------------------------------------------
__global__ __launch_bounds__(256) void rope_q_kernel(float* __restrict__ Y)
{
    int idx = blockIdx.x * 256 + threadIdx.x;
    int j = idx & 31;
    int rest = idx >> 5;
    int h = rest & 7;  rest >>= 3;
    int t = rest & (kT - 1);
    int b = rest >> 11;
    size_t base = (size_t)(b * kT + t) * NTOT + Q_OFF + h * kD;
    float inv_freq = powf(kTHETA, -(float)j * (1.0f / 32.0f));
    float ang = (float)t * inv_freq;
    float c = cosf(ang), s = sinf(ang);
    float x1 = Y[base + 64 + j];
    float x2 = Y[base + 96 + j];
    Y[base + 64 + j] = x1 * c - x2 * s;
    Y[base + 96 + j] = x1 * s + x2 * c;
}

// Gated compress for main KV + RoPE on ck. One block(128) per (b,g,h in HKV).
__global__ __launch_bounds__(128) void compress_c_kernel(
    const float* __restrict__ Y, const float* __restrict__ ape_c,
    float* __restrict__ ck, float* __restrict__ cv)
{
    int bid = blockIdx.x;
    int h = bid & 3;
    int g = (bid >> 2) & (kG - 1);
    int b = bid >> 11;
    int d = threadIdx.x;
    float kv[kRATIO], vv[kRATIO], gv[kRATIO];
    #pragma unroll
    for (int r = 0; r < kRATIO; ++r) {
        size_t row = (size_t)(b * kT + g * kRATIO + r) * NTOT;
        kv[r] = Y[row + CK_OFF + h * kD + d];
        vv[r] = Y[row + CV_OFF + h * kD + d];
        gv[r] = Y[row + CG_OFF + h * kD + d] + ape_c[(r * kHKV + h) * kD + d];
    }
    float m = fmaxf(fmaxf(gv[0], gv[1]), fmaxf(gv[2], gv[3]));
    float ka = 0.f, va = 0.f, den = 0.f;
    #pragma unroll
    for (int r = 0; r < kRATIO; ++r) {
        float e = expf(gv[r] - m);
        den += e;
        ka += kv[r] * e;
        va += vv[r] * e;
    }
    ka /= den; va /= den;
    size_t obase = ((size_t)(b * kG + g) * kHKV + h) * kD;
    cv[obase + d] = va;
    __shared__ float cks[kD];
    cks[d] = ka;
    __syncthreads();
    int pos = 4 * g + 3;
    float out;
    if (d < 64) {
        out = cks[d];
    } else if (d < 96) {
        int j = d - 64;
        float inv_freq = powf(kTHETA, -(float)j * (1.0f / 32.0f));
        float ang = (float)pos * inv_freq;
        out = cks[d] * cosf(ang) - cks[d + 32] * sinf(ang);
    } else {
        int j = d - 96;
        float inv_freq = powf(kTHETA, -(float)j * (1.0f / 32.0f));
        float ang = (float)pos * inv_freq;
        out = cks[d - 32] * sinf(ang) + cks[d] * cosf(ang);
    }
    ck[obase + d] = out;
}

// ---------------------------------------------------------------------------
// Weight concat for the fp64 indexer GEMM: Wcat = [Wiq | Wik | Wig] (1024x1536)
// ---------------------------------------------------------------------------
__global__ __launch_bounds__(256) void concat_w_kernel(
    const float* __restrict__ Wiq, const float* __restrict__ Wik,
    const float* __restrict__ Wig, float* __restrict__ Wcat)
{
    int idx = blockIdx.x * 256 + threadIdx.x;      // per float4; 1536 blocks
    int row = idx / 384;
    int col = (idx - row * 384) * 4;
    float4 v;
    if (col < 512)       v = *(const float4*)(Wiq + (size_t)row * 512 + col);
    else if (col < 1024) v = *(const float4*)(Wik + (size_t)row * 512 + col - 512);
    else                 v = *(const float4*)(Wig + (size_t)row * 512 + col - 1024);
    *(float4*)(Wcat + (size_t)row * PLD + col) = v;
}

// ---------------------------------------------------------------------------
// Tiled fp64 GEMM: P(8192x1536 f64) = x(8192x1024 f32) @ Wcat(1024x1536 f32).
// f32->f64 convert at LDS staging (amortized). 64x64 tile, 4x4 micro, BK=16.
// Selection is a discontinuous argmax; fp64 products of f32 inputs are exact,
// so ordering matches the reference's fp32 boundary gaps with huge margin.
// ---------------------------------------------------------------------------
__global__ __launch_bounds__(256) void proj_f64_kernel(
    const float* __restrict__ x, const float* __restrict__ W,
    double* __restrict__ P)
{
    __shared__ double As[16][65];
    __shared__ double Bs[16][68];
    const int tid = threadIdx.x;
    const int bx = blockIdx.x, by = blockIdx.y;
    const int tx = tid & 15, ty = tid >> 4;
    const int arow = tid >> 2;
    const int akq  = (tid & 3) << 2;
    const int brow = tid >> 4;
    const int bcol = (tid & 15) << 2;
    const float* Ap = x + (size_t)(by * 64 + arow) * kC + akq;
    const float* Bp = W + (size_t)brow * PLD + bx * 64 + bcol;
    double acc[4][4] = {};
    for (int k0 = 0; k0 < kC; k0 += 16) {
        float4 a4 = *(const float4*)(Ap + k0);
        float4 b4 = *(const float4*)(Bp + (size_t)k0 * PLD);
        __syncthreads();
        As[akq + 0][arow] = (double)a4.x;
        As[akq + 1][arow] = (double)a4.y;
        As[akq + 2][arow] = (double)a4.z;
        As[akq + 3][arow] = (double)a4.w;
        Bs[brow][bcol + 0] = (double)b4.x;
        Bs[brow][bcol + 1] = (double)b4.y;
        Bs[brow][bcol + 2] = (double)b4.z;
        Bs[brow][bcol + 3] = (double)b4.w;
        __syncthreads();
        #pragma unroll
        for (int kk = 0; kk < 16; ++kk) {
            double a[4];
            #pragma unroll
            for (int i = 0; i < 4; ++i) a[i] = As[kk][ty * 4 + i];
            #pragma unroll
            for (int j = 0; j < 4; ++j) {
                double bv = Bs[kk][tx * 4 + j];
                #pragma unroll
                for (int i = 0; i < 4; ++i)
                    acc[i][j] = fma(a[i], bv, acc[i][j]);
            }
        }
    }
    #pragma unroll
    for (int i = 0; i < 4; ++i)
        #pragma unroll
        for (int j = 0; j < 4; ++j)
            P[(size_t)(by * 64 + ty * 4 + i) * PLD + bx * 64 + tx * 4 + j] = acc[i][j];
}

// Gating epilogue: ikeys64[b,g,h,:] = rmsnorm(sum_r ki*softmax(gi+ape)).
// One wave per (b,g,h); reads ki/gi fp64 from P.
__global__ __launch_bounds__(64) void gate_i_kernel(
    const double* __restrict__ P, const float* __restrict__ ape_i,
    double* __restrict__ ikeys64)
{
    int bid = blockIdx.x;              // (b*512+g)*8+h
    int h = bid & 7;
    int g = (bid >> 3) & (kG - 1);
    int b = bid >> 12;
    int lane = threadIdx.x;
    double kk[kRATIO], gg[kRATIO];
    #pragma unroll
    for (int r = 0; r < kRATIO; ++r) {
        size_t row = (size_t)(b * kT + g * kRATIO + r) * PLD;
        kk[r] = P[row + P_KI + h * kDI + lane];
        gg[r] = P[row + P_GI + h * kDI + lane] + (double)ape_i[(r * kHI + h) * kDI + lane];
    }
    double m = fmax(fmax(gg[0], gg[1]), fmax(gg[2], gg[3]));
    double acc = 0.0, den = 0.0;
    #pragma unroll
    for (int r = 0; r < kRATIO; ++r) {
        double e = exp(gg[r] - m);
        den += e;
        acc += kk[r] * e;
    }
    acc /= den;
    double ss = waveReduceSumD(acc * acc);
    double scale = 1.0 / sqrt(ss * (1.0 / kDI) + 1e-6);
    ikeys64[((size_t)(b * kG + g) * kHI + h) * kDI + lane] = acc * scale;
}

// rmsnorm iq columns of P in place (per (row,h) over DI=64). Block=512 (8 waves).
__global__ __launch_bounds__(512) void rmsiq64_kernel(double* __restrict__ P)
{
    int row = blockIdx.x;
    int tid = threadIdx.x;             // h = tid>>6, lane = tid&63
    double* p = P + (size_t)row * PLD + P_IQ + tid;
    double v = *p;
    double ss = v * v;
    #pragma unroll
    for (int m = 32; m > 0; m >>= 1) ss += __shfl_xor(ss, m, 64);
    double scale = 1.0 / sqrt(ss * (1.0 / kDI) + 1e-6);
    *p = v * scale;
}

#define BM 64
#define BN 64
#define BK 16

// isc64 = (iq @ ikeys^T) / 64 per batch; iq read from P (lda=PLD), fp64.
__global__ __launch_bounds__(256) void isc_f64_kernel(
    const double* __restrict__ P, const double* __restrict__ ikeys64,
    double* __restrict__ isc64)
{
    __shared__ double As[BK][BM + 1];
    __shared__ double Bs[BK][BN + 4];
    const int tid = threadIdx.x;
    const int bx = blockIdx.x, by = blockIdx.y;
    const int b = by >> 5;
    const int tx = tid & 15, ty = tid >> 4;
    const int arow = tid >> 2;
    const int akq  = (tid & 3) << 2;
    const double* Ap = P + (size_t)(by * BM + arow) * PLD + P_IQ + akq;
    const double* Bp = ikeys64 + (size_t)b * kG * 512 + (size_t)(bx * BN + arow) * 512 + akq;
    double acc[4][4] = {};
    for (int k0 = 0; k0 < 512; k0 += BK) {
        double a0 = Ap[k0], a1 = Ap[k0 + 1], a2 = Ap[k0 + 2], a3 = Ap[k0 + 3];
        double b0 = Bp[k0], b1 = Bp[k0 + 1], b2 = Bp[k0 + 2], b3 = Bp[k0 + 3];
        __syncthreads();
        As[akq + 0][arow] = a0; As[akq + 1][arow] = a1;
        As[akq + 2][arow] = a2; As[akq + 3][arow] = a3;
        Bs[akq + 0][arow] = b0; Bs[akq + 1][arow] = b1;
        Bs[akq + 2][arow] = b2; Bs[akq + 3][arow] = b3;
        __syncthreads();
        #pragma unroll
        for (int kk = 0; kk < BK; ++kk) {
            double a[4];
            #pragma unroll
            for (int i = 0; i < 4; ++i) a[i] = As[kk][ty * 4 + i];
            #pragma unroll
            for (int j = 0; j < 4; ++j) {
                double bv = Bs[kk][tx * 4 + j];
                #pragma unroll
                for (int i = 0; i < 4; ++i)
                    acc[i][j] = fma(a[i], bv, acc[i][j]);
            }
        }
    }
    #pragma unroll
    for (int i = 0; i < 4; ++i)
        #pragma unroll
        for (int j = 0; j < 4; ++j)
            isc64[(size_t)(by * BM + ty * 4 + i) * kG + bx * BN + tx * 4 + j] =
                acc[i][j] * (1.0 / 64.0);
}

// ---------------------------------------------------------------------------
// Top-k (set semantics suffice downstream; keep exact jax ordering anyway).
// ---------------------------------------------------------------------------
__global__ __launch_bounds__(256) void topk_kernel(
    const double* __restrict__ isc, int* __restrict__ sel, int* __restrict__ cnt)
{
    int bt = blockIdx.x;
    int t = bt & (kT - 1);
    int tid = threadIdx.x;
    __shared__ double sv[kG];
    __shared__ int si[kG];
    const double* row = isc + (size_t)bt * kG;
    for (int g = tid; g < kG; g += 256) {
        bool causal = (4 * g + 3) <= t;
        sv[g] = causal ? row[g] : (double)kNEG;
        si[g] = g;
    }
    __syncthreads();
    for (int k = 2; k <= kG; k <<= 1) {
        for (int j = k >> 1; j > 0; j >>= 1) {
            for (int i = tid; i < kG; i += 256) {
                int l = i ^ j;
                if (l > i) {
                    double vi = sv[i], vl = sv[l];
                    int ii = si[i], il = si[l];
                    bool l_first = (vl > vi) || (vl == vi && il < ii);
                    bool desc = ((i & k) == 0);
                    if (desc ? l_first : !l_first) {
                        sv[i] = vl; sv[l] = vi;
                        si[i] = il; si[l] = ii;
                    }
                }
            }
            __syncthreads();
        }
    }
    int count = (t >= 3) ? (((t - 3) >> 2) + 1) : 0;
    int n = count < kTOPK ? count : kTOPK;
    if (tid < kTOPK) sel[(size_t)bt * kTOPK + tid] = (tid < n) ? si[tid] : 0;
    if (tid == 0) cnt[bt] = n;
}

// ---------------------------------------------------------------------------
// Sparse gathered attention -> split bf16 [hi|lo] rows for the Wa MFMA GEMM.
// ---------------------------------------------------------------------------
__global__ __launch_bounds__(64) void attn_kernel(
    const float* __restrict__ Y, const float* __restrict__ ck,
    const float* __restrict__ cv, const int* __restrict__ sel,
    const int* __restrict__ cnt, unsigned short* __restrict__ acat)
{
    int bid = blockIdx.x;
    int h = bid & 7;
    int row = bid >> 3;
    int b = row >> 11;
    int lane = threadIdx.x;
    __shared__ float qs[kD];
    __shared__ float ws[kTOPK];
    __shared__ int gs[kTOPK];
    const float* qp = Y + (size_t)row * NTOT + Q_OFF + h * kD;
    qs[lane] = qp[lane];
    qs[lane + 64] = qp[lane + 64];
    __syncthreads();
    int n = cnt[row];
    unsigned short* outp = acat + (size_t)row * 2048 + h * kD;
    float acc0 = 0.f, acc1 = 0.f;
    if (n > 0) {
        int kvh = h >> 1;
        float score = kNEG;
        int g = 0;
        if (lane < n) {
            g = sel[(size_t)row * kTOPK + lane];
            const float* ckp = ck + ((size_t)(b * kG + g) * kHKV + kvh) * kD;
            float s = 0.f;
            #pragma unroll
            for (int d = 0; d < kD; d += 4) {
                float4 c4 = *(const float4*)(ckp + d);
                s += qs[d] * c4.x + qs[d + 1] * c4.y + qs[d + 2] * c4.z + qs[d + 3] * c4.w;
            }
            score = s * 0.08838834764831845f;
        }
        float m = waveReduceMax(score);
        float p = (lane < n) ? expf(score - m) : 0.f;
        float sum = waveReduceSum(p);
        float w = p / sum;
        ws[lane] = w;
        gs[lane] = g;
        __syncthreads();
        for (int j = 0; j < n; ++j) {
            float wj = ws[j];
            const float* cvp = cv + ((size_t)(b * kG + gs[j]) * kHKV + kvh) * kD;
            acc0 = fmaf(wj, cvp[lane], acc0);
            acc1 = fmaf(wj, cvp[lane + 64], acc1);
        }
    }
    unsigned short h0 = f2bf(acc0), h1 = f2bf(acc1);
    outp[lane] = h0;
    outp[lane + 64] = h1;
    outp[1024 + lane] = f2bf(acc0 - bf2f(h0));
    outp[1024 + lane + 64] = f2bf(acc1 - bf2f(h1));
}

// Row rms scales for r (RANK=512 per row). One wave per row.
__global__ __launch_bounds__(64) void rms_rows_kernel(
    const float* __restrict__ R, float* __restrict__ scale)
{
    int row = blockIdx.x;
    int lane = threadIdx.x;
    const float* p = R + (size_t)row * kRANK;
    float s = 0.f;
    #pragma unroll
    for (int i = 0; i < kRANK / 64; ++i) {
        float v = p[lane + i * 64];
        s = fmaf(v, v, s);
    }
    s = waveReduceSum(s);
    if (lane == 0) scale[row] = 1.0f / sqrtf(s * (1.0f / kRANK) + 1e-6f);
}

// ---------------------------------------------------------------------------
extern "C" void kernel_launch(void* const* d_in, const int* in_sizes, int n_in,
                              void* d_out, int out_size, void* d_ws, size_t ws_size,
                              hipStream_t stream)
{
    const float* x    = (const float*)d_in[0];
    const float* Wq   = (const float*)d_in[1];
    const float* Wck  = (const float*)d_in[2];
    const float* Wcv  = (const float*)d_in[3];
    const float* Wcg  = (const float*)d_in[4];
    const float* ape_c= (const float*)d_in[5];
    const float* Wiq  = (const float*)d_in[6];
    const float* Wik  = (const float*)d_in[7];
    const float* Wig  = (const float*)d_in[8];
    const float* ape_i= (const float*)d_in[9];
    const float* Wa   = (const float*)d_in[10];
    const float* Wb   = (const float*)d_in[11];
    float* out = (float*)d_out;

    const int M = kB * kT;  // 8192

    // Workspace carve (~222 MB).
    // P (fp64, 100.7 MB) is dead after isc_f64; Y (fp32, 83.9 MB) aliases it
    // (value-path GEMM runs strictly after isc in stream order).
    char* p = (char*)d_ws;
    double* P       = (double*)p;              p += (size_t)M * PLD * 8;        // 100.7 MB
    double* ikeys64 = (double*)p;              p += (size_t)kB * kG * 512 * 8;  //   8.4 MB
    double* isc64   = (double*)p;              p += (size_t)M * kG * 8;         //  33.6 MB
    float* ck       = (float*)p;               p += (size_t)kB * kG * kHKV * kD * 4;
    float* cv       = (float*)p;               p += (size_t)kB * kG * kHKV * kD * 4;
    float* rbuf     = (float*)p;               p += (size_t)M * kRANK * 4;      //  16.8 MB
    float* rscale   = (float*)p;               p += (size_t)M * 4;
    int* sel        = (int*)p;                 p += (size_t)M * kTOPK * 4;
    int* cnt        = (int*)p;                 p += (size_t)M * 4;
    unsigned short* xcat  = (unsigned short*)p; p += (size_t)M * 2048 * 2;      //  33.6 MB
    unsigned short* Wtall = (unsigned short*)p; p += (size_t)NTOT * 2048 * 2;   //  10.5 MB
    unsigned short* Wat   = (unsigned short*)p; p += (size_t)kRANK * 2048 * 2;
    unsigned short* Wbt   = (unsigned short*)p; p += (size_t)kC * 1024 * 2;
    float* Wcat     = (float*)p;               p += (size_t)kC * PLD * 4;       //   6.3 MB
    // Aliases (lifetime-disjoint):
    float* Y = (float*)P;                        // value-path proj output
    unsigned short* acat  = xcat;                // attn out over x-split
    unsigned short* rncat = (unsigned short*)isc64; // rmsnorm(r) split over isc

    // --- fp64 indexer chain (must finish before Y overwrites P) ---
    concat_w_kernel<<<(kC * PLD / 4) / 256, 256, 0, stream>>>(Wiq, Wik, Wig, Wcat);
    proj_f64_kernel<<<dim3(PLD / 64, M / 64), 256, 0, stream>>>(x, Wcat, P);
    gate_i_kernel<<<kB * kG * kHI, 64, 0, stream>>>(P, ape_i, ikeys64);
    rmsiq64_kernel<<<M, 512, 0, stream>>>(P);
    isc_f64_kernel<<<dim3(kG / BN, M / BM), 256, 0, stream>>>(P, ikeys64, isc64);
    topk_kernel<<<kB * kT, 256, 0, stream>>>(isc64, sel, cnt);

    // --- value path ---
    split_rows_kernel<<<(size_t)M * kC / 4 / 256, 256, 0, stream>>>(
        x, xcat, kC, 8, nullptr);
    transpose_split_kernel<<<dim3(kC / 64, 1024 / 64), 256, 0, stream>>>(
        Wq, 1024, kC, Wtall + (size_t)Q_OFF * 2048);
    transpose_split_kernel<<<dim3(kC / 64, 512 / 64), 256, 0, stream>>>(
        Wck, 512, kC, Wtall + (size_t)CK_OFF * 2048);
    transpose_split_kernel<<<dim3(kC / 64, 512 / 64), 256, 0, stream>>>(
        Wcv, 512, kC, Wtall + (size_t)CV_OFF * 2048);
    transpose_split_kernel<<<dim3(kC / 64, 512 / 64), 256, 0, stream>>>(
        Wcg, 512, kC, Wtall + (size_t)CG_OFF * 2048);

    gemm_mfma_kernel<<<dim3(NTOT / 128, M / 128), 256, 0, stream>>>(
        xcat, Wtall, Y, NTOT, kC);

    rope_q_kernel<<<(kB * kT * kH * 32) / 256, 256, 0, stream>>>(Y);
    compress_c_kernel<<<kB * kG * kHKV, 128, 0, stream>>>(Y, ape_c, ck, cv);

    attn_kernel<<<kB * kT * kH, 64, 0, stream>>>(Y, ck, cv, sel, cnt, acat);

    split_rows_kernel<<<(size_t)kRANK * kC / 4 / 256, 256, 0, stream>>>(
        Wa, Wat, kC, 8, nullptr);
    gemm_mfma_kernel<<<dim3(kRANK / 128, M / 128), 256, 0, stream>>>(
        acat, Wat, rbuf, kRANK, kC);

    rms_rows_kernel<<<M, 64, 0, stream>>>(rbuf, rscale);
    split_rows_kernel<<<(size_t)M * kRANK / 4 / 256, 256, 0, stream>>>(
        rbuf, rncat, kRANK, 7, rscale);
    transpose_split_kernel<<<dim3(kRANK / 64, kC / 64), 256, 0, stream>>>(
        Wb, kC, kRANK, Wbt);
    gemm_mfma_kernel<<<dim3(kC / 128, M / 128), 256, 0, stream>>>(
        rncat, Wbt, out, kC, kRANK);

    (void)in_sizes; (void)n_in; (void)out_size; (void)ws_size;
}

// Round 5
// 1567.440 us; speedup vs baseline: 1.8729x; 1.1454x over previous
//
#include <hip/hip_runtime.h>
#include <hip/hip_bf16.h>
#include <math.h>

// Problem constants
constexpr int kB = 4, kT = 2048, kC = 1024;
constexpr int kH = 8, kHKV = 4, kD = 128;
constexpr int kRATIO = 4, kG = 512;
constexpr int kHI = 8, kDI = 64;
constexpr int kTOPK = 64, kRANK = 512;
constexpr float kTHETA = 160000.0f;
constexpr float kNEG = -1e30f;

// Projection buffer column layout (value path; indexer path is fp64)
constexpr int NTOT = 2560;
constexpr int Q_OFF = 0;      // 1024 cols (H*D)
constexpr int CK_OFF = 1024;  // 512
constexpr int CV_OFF = 1536;  // 512
constexpr int CG_OFF = 2048;  // 512

// fp64 indexer projection buffer P: 8192 x 1536 (iq | ki | gi)
constexpr int PLD = 1536;
constexpr int P_IQ = 0, P_KI = 512, P_GI = 1024;

typedef short short8 __attribute__((ext_vector_type(8)));
typedef float floatx4 __attribute__((ext_vector_type(4)));

__device__ inline float waveReduceSum(float v) {
    #pragma unroll
    for (int m = 32; m > 0; m >>= 1) v += __shfl_xor(v, m, 64);
    return v;
}
__device__ inline double waveReduceSumD(double v) {
    #pragma unroll
    for (int m = 32; m > 0; m >>= 1) v += __shfl_xor(v, m, 64);
    return v;
}
__device__ inline float waveReduceMax(float v) {
    #pragma unroll
    for (int m = 32; m > 0; m >>= 1) v = fmaxf(v, __shfl_xor(v, m, 64));
    return v;
}

// bf16 round-to-nearest-even (values are finite/well-behaved; no NaN path)
__device__ inline unsigned short f2bf(float f) {
    union { float f; unsigned int u; } v; v.f = f;
    unsigned int r = v.u + 0x7FFFu + ((v.u >> 16) & 1u);
    return (unsigned short)(r >> 16);
}
__device__ inline float bf2f(unsigned short h) {
    union { unsigned int u; float f; } v; v.u = ((unsigned int)h) << 16;
    return v.f;
}

// ---------------------------------------------------------------------------
// split_rows: in (rows x K fp32, optional per-row scale) -> out (rows x 2K bf16)
// ---------------------------------------------------------------------------
__global__ __launch_bounds__(256) void split_rows_kernel(
    const float* __restrict__ in, unsigned short* __restrict__ out,
    int K, int kshift, const float* __restrict__ rowScale)
{
    int idx = blockIdx.x * 256 + threadIdx.x;
    int row = idx >> kshift;
    int kc = (idx & ((1 << kshift) - 1)) << 2;
    float4 v = *(const float4*)(in + (size_t)row * K + kc);
    if (rowScale) {
        float s = rowScale[row];
        v.x *= s; v.y *= s; v.z *= s; v.w *= s;
    }
    unsigned short h[4], l[4];
    float vv[4] = {v.x, v.y, v.z, v.w};
    #pragma unroll
    for (int i = 0; i < 4; ++i) {
        h[i] = f2bf(vv[i]);
        l[i] = f2bf(vv[i] - bf2f(h[i]));
    }
    size_t ob = (size_t)row * (2 * K);
    uint2 hw, lw;
    hw.x = (unsigned)h[0] | ((unsigned)h[1] << 16);
    hw.y = (unsigned)h[2] | ((unsigned)h[3] << 16);
    lw.x = (unsigned)l[0] | ((unsigned)l[1] << 16);
    lw.y = (unsigned)l[2] | ((unsigned)l[3] << 16);
    *(uint2*)(out + ob + kc) = hw;
    *(uint2*)(out + ob + K + kc) = lw;
}

// ---------------------------------------------------------------------------
// transpose_split: W (K x N fp32, row-major) -> Wt (N x 2K bf16) [hi|lo]
// ---------------------------------------------------------------------------
__global__ __launch_bounds__(256) void transpose_split_kernel(
    const float* __restrict__ W, int N, int K, unsigned short* __restrict__ Wt)
{
    __shared__ float Ws[64][68];
    int k0 = blockIdx.x * 64, n0 = blockIdx.y * 64;
    int tid = threadIdx.x;
    #pragma unroll
    for (int it = 0; it < 4; ++it) {
        int krow = (tid >> 4) + it * 16;
        float4 v = *(const float4*)(W + (size_t)(k0 + krow) * N + n0 + (tid & 15) * 4);
        *(float4*)&Ws[krow][(tid & 15) * 4] = v;
    }
    __syncthreads();
    #pragma unroll
    for (int it = 0; it < 2; ++it) {
        int idx = tid + it * 256;
        int nrow = idx >> 3;
        int kc8 = (idx & 7) * 8;
        unsigned short h[8], l[8];
        #pragma unroll
        for (int j = 0; j < 8; ++j) {
            float v = Ws[kc8 + j][nrow];
            h[j] = f2bf(v);
            l[j] = f2bf(v - bf2f(h[j]));
        }
        size_t ob = (size_t)(n0 + nrow) * (2 * K) + k0;
        uint4 hw, lw;
        hw.x = (unsigned)h[0] | ((unsigned)h[1] << 16);
        hw.y = (unsigned)h[2] | ((unsigned)h[3] << 16);
        hw.z = (unsigned)h[4] | ((unsigned)h[5] << 16);
        hw.w = (unsigned)h[6] | ((unsigned)h[7] << 16);
        lw.x = (unsigned)l[0] | ((unsigned)l[1] << 16);
        lw.y = (unsigned)l[2] | ((unsigned)l[3] << 16);
        lw.z = (unsigned)l[4] | ((unsigned)l[5] << 16);
        lw.w = (unsigned)l[6] | ((unsigned)l[7] << 16);
        *(uint4*)(Wt + ob + kc8) = hw;
        *(uint4*)(Wt + ob + K + kc8) = lw;
    }
}

// ---------------------------------------------------------------------------
// Split-bf16 MFMA GEMM: C(MxN f32) = A * B^T using bf16 16x16x32 MFMA.
// K' = 3*Kin passes: [A_hi*B_hi, A_lo*B_hi, A_hi*B_lo] -> fp32-grade.
// ---------------------------------------------------------------------------
#define TSTRIDE 40  // 32 bf16 + 8 pad

__global__ __launch_bounds__(256) void gemm_mfma_kernel(
    const unsigned short* __restrict__ A,
    const unsigned short* __restrict__ B,
    float* __restrict__ C, int ldc, int Kin)
{
    __shared__ unsigned short As[128 * TSTRIDE];
    __shared__ unsigned short Bs[128 * TSTRIDE];
    const int tid = threadIdx.x;
    const int n0 = blockIdx.x * 128, m0 = blockIdx.y * 128;
    const int w = tid >> 6, lane = tid & 63;
    const int q = lane >> 4, r = lane & 15;
    const int wm = (w & 1) * 64, wn = (w >> 1) * 64;
    const int lda = 2 * Kin, ldb = 2 * Kin;
    const int srow = tid >> 2;
    const int sko = (tid & 3) * 8;

    floatx4 acc[4][4] = {};
    const int KT = 3 * Kin;
    for (int k0 = 0; k0 < KT; k0 += 32) {
        int ka = (k0 < 2 * Kin) ? k0 : k0 - 2 * Kin;
        int kb = (k0 < Kin) ? k0 : k0 - Kin;
        __syncthreads();
        #pragma unroll
        for (int rep = 0; rep < 2; ++rep) {
            int row = srow + rep * 64;
            uint4 av = *(const uint4*)(A + (size_t)(m0 + row) * lda + ka + sko);
            uint4 bv = *(const uint4*)(B + (size_t)(n0 + row) * ldb + kb + sko);
            *(uint4*)&As[row * TSTRIDE + sko] = av;
            *(uint4*)&Bs[row * TSTRIDE + sko] = bv;
        }
        __syncthreads();
        short8 af[4], bf[4];
        #pragma unroll
        for (int i = 0; i < 4; ++i)
            af[i] = *(const short8*)&As[(wm + i * 16 + r) * TSTRIDE + q * 8];
        #pragma unroll
        for (int j = 0; j < 4; ++j)
            bf[j] = *(const short8*)&Bs[(wn + j * 16 + r) * TSTRIDE + q * 8];
        #pragma unroll
        for (int i = 0; i < 4; ++i)
            #pragma unroll
            for (int j = 0; j < 4; ++j)
                acc[i][j] = __builtin_amdgcn_mfma_f32_16x16x32_bf16(
                    af[i], bf[j], acc[i][j], 0, 0, 0);
    }
    #pragma unroll
    for (int i = 0; i < 4; ++i)
        #pragma unroll
        for (int j = 0; j < 4; ++j)
            #pragma unroll
            for (int reg = 0; reg < 4; ++reg)
                C[(size_t)(m0 + wm + i * 16 + q * 4 + reg) * ldc
                  + n0 + wn + j * 16 + r] = acc[i][j][reg];
}

// ---------------------------------------------------------------------------
// In-place partial RoPE on q columns of Y.
// ---------------------------------------------------------------------------
__global__ __launch_bounds__(256) void rope_q_kernel(float* __restrict__ Y)
{
    int idx = blockIdx.x * 256 + threadIdx.x;
    int j = idx & 31;
    int rest = idx >> 5;
    int h = rest & 7;  rest >>= 3;
    int t = rest & (kT - 1);
    int b = rest >> 11;
    size_t base = (size_t)(b * kT + t) * NTOT + Q_OFF + h * kD;
    float inv_freq = powf(kTHETA, -(float)j * (1.0f / 32.0f));
    float ang = (float)t * inv_freq;
    float c = cosf(ang), s = sinf(ang);
    float x1 = Y[base + 64 + j];
    float x2 = Y[base + 96 + j];
    Y[base + 64 + j] = x1 * c - x2 * s;
    Y[base + 96 + j] = x1 * s + x2 * c;
}

// Gated compress for main KV + RoPE on ck. One block(128) per (b,g,h in HKV).
__global__ __launch_bounds__(128) void compress_c_kernel(
    const float* __restrict__ Y, const float* __restrict__ ape_c,
    float* __restrict__ ck, float* __restrict__ cv)
{
    int bid = blockIdx.x;
    int h = bid & 3;
    int g = (bid >> 2) & (kG - 1);
    int b = bid >> 11;
    int d = threadIdx.x;
    float kv[kRATIO], vv[kRATIO], gv[kRATIO];
    #pragma unroll
    for (int r = 0; r < kRATIO; ++r) {
        size_t row = (size_t)(b * kT + g * kRATIO + r) * NTOT;
        kv[r] = Y[row + CK_OFF + h * kD + d];
        vv[r] = Y[row + CV_OFF + h * kD + d];
        gv[r] = Y[row + CG_OFF + h * kD + d] + ape_c[(r * kHKV + h) * kD + d];
    }
    float m = fmaxf(fmaxf(gv[0], gv[1]), fmaxf(gv[2], gv[3]));
    float ka = 0.f, va = 0.f, den = 0.f;
    #pragma unroll
    for (int r = 0; r < kRATIO; ++r) {
        float e = expf(gv[r] - m);
        den += e;
        ka += kv[r] * e;
        va += vv[r] * e;
    }
    ka /= den; va /= den;
    size_t obase = ((size_t)(b * kG + g) * kHKV + h) * kD;
    cv[obase + d] = va;
    __shared__ float cks[kD];
    cks[d] = ka;
    __syncthreads();
    int pos = 4 * g + 3;
    float out;
    if (d < 64) {
        out = cks[d];
    } else if (d < 96) {
        int j = d - 64;
        float inv_freq = powf(kTHETA, -(float)j * (1.0f / 32.0f));
        float ang = (float)pos * inv_freq;
        out = cks[d] * cosf(ang) - cks[d + 32] * sinf(ang);
    } else {
        int j = d - 96;
        float inv_freq = powf(kTHETA, -(float)j * (1.0f / 32.0f));
        float ang = (float)pos * inv_freq;
        out = cks[d - 32] * sinf(ang) + cks[d] * cosf(ang);
    }
    ck[obase + d] = out;
}

// ---------------------------------------------------------------------------
// Weight concat for the fp64 indexer GEMM: Wcat = [Wiq | Wik | Wig] (1024x1536)
// ---------------------------------------------------------------------------
__global__ __launch_bounds__(256) void concat_w_kernel(
    const float* __restrict__ Wiq, const float* __restrict__ Wik,
    const float* __restrict__ Wig, float* __restrict__ Wcat)
{
    int idx = blockIdx.x * 256 + threadIdx.x;      // per float4; 1536 blocks
    int row = idx / 384;
    int col = (idx - row * 384) * 4;
    float4 v;
    if (col < 512)       v = *(const float4*)(Wiq + (size_t)row * 512 + col);
    else if (col < 1024) v = *(const float4*)(Wik + (size_t)row * 512 + col - 512);
    else                 v = *(const float4*)(Wig + (size_t)row * 512 + col - 1024);
    *(float4*)(Wcat + (size_t)row * PLD + col) = v;
}

// ---------------------------------------------------------------------------
// Tiled fp64 GEMM: P(8192x1536 f64) = x(8192x1024 f32) @ Wcat(1024x1536 f32).
// 128x64 tile, 8x4 micro-tile. Bank-conflict-free micro-reads:
//   cols mapped tx + 16*j -> 16 lanes hit 16 consecutive double slots = all
//   32 banks; A-reads are 4-address broadcasts (2-way = free).
// f32->f64 conversion at LDS staging (amortized over 32 FMAs/kk).
// ---------------------------------------------------------------------------
#define PBM 128
#define PBN 64
#define PBK 16

__global__ __launch_bounds__(256) void proj_f64_kernel(
    const float* __restrict__ x, const float* __restrict__ W,
    double* __restrict__ P)
{
    __shared__ double As[PBK][129];   // [k][row], odd pad
    __shared__ double Bs[PBK][68];    // [k][col]
    const int tid = threadIdx.x;
    const int bx = blockIdx.x, by = blockIdx.y;
    const int tx = tid & 15, ty = tid >> 4;
    // A staging: row ar = tid>>1, k-offset ak = (tid&1)*8 (8 floats = 2 float4)
    const int ar = tid >> 1;
    const int ak = (tid & 1) * 8;
    // B staging: row br = tid>>4, col bc + 16k (stride-16 scalar loads, lane-coalesced)
    const int br = tid >> 4;
    const int bc = tid & 15;
    const float* Ap = x + (size_t)(by * PBM + ar) * kC + ak;
    const float* Bp = W + (size_t)br * PLD + bx * PBN + bc;
    double acc[8][4] = {};
    for (int k0 = 0; k0 < kC; k0 += PBK) {
        float4 a0 = *(const float4*)(Ap + k0);
        float4 a1 = *(const float4*)(Ap + k0 + 4);
        const float* bp = Bp + (size_t)k0 * PLD;
        float b0 = bp[0], b1 = bp[16], b2 = bp[32], b3 = bp[48];
        __syncthreads();
        As[ak + 0][ar] = (double)a0.x;
        As[ak + 1][ar] = (double)a0.y;
        As[ak + 2][ar] = (double)a0.z;
        As[ak + 3][ar] = (double)a0.w;
        As[ak + 4][ar] = (double)a1.x;
        As[ak + 5][ar] = (double)a1.y;
        As[ak + 6][ar] = (double)a1.z;
        As[ak + 7][ar] = (double)a1.w;
        Bs[br][bc]      = (double)b0;
        Bs[br][bc + 16] = (double)b1;
        Bs[br][bc + 32] = (double)b2;
        Bs[br][bc + 48] = (double)b3;
        __syncthreads();
        #pragma unroll
        for (int kk = 0; kk < PBK; ++kk) {
            double a[8], b[4];
            #pragma unroll
            for (int i = 0; i < 8; ++i) a[i] = As[kk][ty * 8 + i];
            #pragma unroll
            for (int j = 0; j < 4; ++j) b[j] = Bs[kk][tx + 16 * j];
            #pragma unroll
            for (int i = 0; i < 8; ++i)
                #pragma unroll
                for (int j = 0; j < 4; ++j)
                    acc[i][j] = fma(a[i], b[j], acc[i][j]);
        }
    }
    #pragma unroll
    for (int i = 0; i < 8; ++i)
        #pragma unroll
        for (int j = 0; j < 4; ++j)
            P[(size_t)(by * PBM + ty * 8 + i) * PLD + bx * PBN + tx + 16 * j] = acc[i][j];
}

// Gating epilogue: ikeys64[b,g,h,:] = rmsnorm(sum_r ki*softmax(gi+ape)).
__global__ __launch_bounds__(64) void gate_i_kernel(
    const double* __restrict__ P, const float* __restrict__ ape_i,
    double* __restrict__ ikeys64)
{
    int bid = blockIdx.x;              // (b*512+g)*8+h
    int h = bid & 7;
    int g = (bid >> 3) & (kG - 1);
    int b = bid >> 12;
    int lane = threadIdx.x;
    double kk[kRATIO], gg[kRATIO];
    #pragma unroll
    for (int r = 0; r < kRATIO; ++r) {
        size_t row = (size_t)(b * kT + g * kRATIO + r) * PLD;
        kk[r] = P[row + P_KI + h * kDI + lane];
        gg[r] = P[row + P_GI + h * kDI + lane] + (double)ape_i[(r * kHI + h) * kDI + lane];
    }
    double m = fmax(fmax(gg[0], gg[1]), fmax(gg[2], gg[3]));
    double acc = 0.0, den = 0.0;
    #pragma unroll
    for (int r = 0; r < kRATIO; ++r) {
        double e = exp(gg[r] - m);
        den += e;
        acc += kk[r] * e;
    }
    acc /= den;
    double ss = waveReduceSumD(acc * acc);
    double scale = 1.0 / sqrt(ss * (1.0 / kDI) + 1e-6);
    ikeys64[((size_t)(b * kG + g) * kHI + h) * kDI + lane] = acc * scale;
}

// rmsnorm iq columns of P in place (per (row,h) over DI=64). Block=512 (8 waves).
__global__ __launch_bounds__(512) void rmsiq64_kernel(double* __restrict__ P)
{
    int row = blockIdx.x;
    int tid = threadIdx.x;
    double* p = P + (size_t)row * PLD + P_IQ + tid;
    double v = *p;
    double ss = v * v;
    #pragma unroll
    for (int m = 32; m > 0; m >>= 1) ss += __shfl_xor(ss, m, 64);
    double scale = 1.0 / sqrt(ss * (1.0 / kDI) + 1e-6);
    *p = v * scale;
}

#define BM 64
#define BN 64
#define BK 16

// isc64 = (iq @ ikeys^T) / 64 per batch; iq read from P (lda=PLD), fp64.
__global__ __launch_bounds__(256) void isc_f64_kernel(
    const double* __restrict__ P, const double* __restrict__ ikeys64,
    double* __restrict__ isc64)
{
    __shared__ double As[BK][BM + 1];
    __shared__ double Bs[BK][BN + 4];
    const int tid = threadIdx.x;
    const int bx = blockIdx.x, by = blockIdx.y;
    const int b = by >> 5;
    const int tx = tid & 15, ty = tid >> 4;
    const int arow = tid >> 2;
    const int akq  = (tid & 3) << 2;
    const double* Ap = P + (size_t)(by * BM + arow) * PLD + P_IQ + akq;
    const double* Bp = ikeys64 + (size_t)b * kG * 512 + (size_t)(bx * BN + arow) * 512 + akq;
    double acc[4][4] = {};
    for (int k0 = 0; k0 < 512; k0 += BK) {
        double a0 = Ap[k0], a1 = Ap[k0 + 1], a2 = Ap[k0 + 2], a3 = Ap[k0 + 3];
        double b0 = Bp[k0], b1 = Bp[k0 + 1], b2 = Bp[k0 + 2], b3 = Bp[k0 + 3];
        __syncthreads();
        As[akq + 0][arow] = a0; As[akq + 1][arow] = a1;
        As[akq + 2][arow] = a2; As[akq + 3][arow] = a3;
        Bs[akq + 0][arow] = b0; Bs[akq + 1][arow] = b1;
        Bs[akq + 2][arow] = b2; Bs[akq + 3][arow] = b3;
        __syncthreads();
        #pragma unroll
        for (int kk = 0; kk < BK; ++kk) {
            double a[4];
            #pragma unroll
            for (int i = 0; i < 4; ++i) a[i] = As[kk][ty * 4 + i];
            #pragma unroll
            for (int j = 0; j < 4; ++j) {
                double bv = Bs[kk][tx * 4 + j];
                #pragma unroll
                for (int i = 0; i < 4; ++i)
                    acc[i][j] = fma(a[i], bv, acc[i][j]);
            }
        }
    }
    #pragma unroll
    for (int i = 0; i < 4; ++i)
        #pragma unroll
        for (int j = 0; j < 4; ++j)
            isc64[(size_t)(by * BM + ty * 4 + i) * kG + bx * BN + tx * 4 + j] =
                acc[i][j] * (1.0 / 64.0);
}

// ---------------------------------------------------------------------------
// Top-k via bitonic sort on uint64 keys: monotone double->u64 map with group
// index embedded in the low 9 bits (2^-43 relative perturbation — only
// reorders exact-tie pairs; index asc tie-break preserved via 511-g).
// ---------------------------------------------------------------------------
__global__ __launch_bounds__(256) void topk_kernel(
    const double* __restrict__ isc, int* __restrict__ sel, int* __restrict__ cnt)
{
    int bt = blockIdx.x;
    int t = bt & (kT - 1);
    int tid = threadIdx.x;
    __shared__ unsigned long long sk[kG];
    const double* row = isc + (size_t)bt * kG;
    for (int g = tid; g < kG; g += 256) {
        bool causal = (4 * g + 3) <= t;
        unsigned long long key;
        if (causal) {
            union { double d; unsigned long long u; } v; v.d = row[g];
            unsigned long long b = v.u;
            key = (b >> 63) ? ~b : (b | 0x8000000000000000ULL);
            key = (key & ~511ULL) | (unsigned long long)(511 - g);
        } else {
            key = (unsigned long long)(511 - g);   // effectively -inf
        }
        sk[g] = key;
    }
    __syncthreads();
    for (int k = 2; k <= kG; k <<= 1) {
        for (int j = k >> 1; j > 0; j >>= 1) {
            #pragma unroll 2
            for (int i = tid; i < kG; i += 256) {
                int l = i ^ j;
                if (l > i) {
                    unsigned long long ki = sk[i], kl = sk[l];
                    bool l_first = kl > ki;           // descending
                    bool desc = ((i & k) == 0);
                    if (desc ? l_first : !l_first) {
                        sk[i] = kl; sk[l] = ki;
                    }
                }
            }
            __syncthreads();
        }
    }
    int count = (t >= 3) ? (((t - 3) >> 2) + 1) : 0;
    int n = count < kTOPK ? count : kTOPK;
    if (tid < kTOPK)
        sel[(size_t)bt * kTOPK + tid] =
            (tid < n) ? (511 - (int)(sk[tid] & 511ULL)) : 0;
    if (tid == 0) cnt[bt] = n;
}

// ---------------------------------------------------------------------------
// Sparse gathered attention -> split bf16 [hi|lo] rows for the Wa MFMA GEMM.
// ---------------------------------------------------------------------------
__global__ __launch_bounds__(64) void attn_kernel(
    const float* __restrict__ Y, const float* __restrict__ ck,
    const float* __restrict__ cv, const int* __restrict__ sel,
    const int* __restrict__ cnt, unsigned short* __restrict__ acat)
{
    int bid = blockIdx.x;
    int h = bid & 7;
    int row = bid >> 3;
    int b = row >> 11;
    int lane = threadIdx.x;
    __shared__ float qs[kD];
    __shared__ float ws[kTOPK];
    __shared__ int gs[kTOPK];
    const float* qp = Y + (size_t)row * NTOT + Q_OFF + h * kD;
    qs[lane] = qp[lane];
    qs[lane + 64] = qp[lane + 64];
    __syncthreads();
    int n = cnt[row];
    unsigned short* outp = acat + (size_t)row * 2048 + h * kD;
    float acc0 = 0.f, acc1 = 0.f;
    if (n > 0) {
        int kvh = h >> 1;
        float score = kNEG;
        int g = 0;
        if (lane < n) {
            g = sel[(size_t)row * kTOPK + lane];
            const float* ckp = ck + ((size_t)(b * kG + g) * kHKV + kvh) * kD;
            float s = 0.f;
            #pragma unroll
            for (int d = 0; d < kD; d += 4) {
                float4 c4 = *(const float4*)(ckp + d);
                s += qs[d] * c4.x + qs[d + 1] * c4.y + qs[d + 2] * c4.z + qs[d + 3] * c4.w;
            }
            score = s * 0.08838834764831845f;
        }
        float m = waveReduceMax(score);
        float p = (lane < n) ? expf(score - m) : 0.f;
        float sum = waveReduceSum(p);
        float w = p / sum;
        ws[lane] = w;
        gs[lane] = g;
        __syncthreads();
        for (int j = 0; j < n; ++j) {
            float wj = ws[j];
            const float* cvp = cv + ((size_t)(b * kG + gs[j]) * kHKV + kvh) * kD;
            acc0 = fmaf(wj, cvp[lane], acc0);
            acc1 = fmaf(wj, cvp[lane + 64], acc1);
        }
    }
    unsigned short h0 = f2bf(acc0), h1 = f2bf(acc1);
    outp[lane] = h0;
    outp[lane + 64] = h1;
    outp[1024 + lane] = f2bf(acc0 - bf2f(h0));
    outp[1024 + lane + 64] = f2bf(acc1 - bf2f(h1));
}

// Row rms scales for r (RANK=512 per row). One wave per row.
__global__ __launch_bounds__(64) void rms_rows_kernel(
    const float* __restrict__ R, float* __restrict__ scale)
{
    int row = blockIdx.x;
    int lane = threadIdx.x;
    const float* p = R + (size_t)row * kRANK;
    float s = 0.f;
    #pragma unroll
    for (int i = 0; i < kRANK / 64; ++i) {
        float v = p[lane + i * 64];
        s = fmaf(v, v, s);
    }
    s = waveReduceSum(s);
    if (lane == 0) scale[row] = 1.0f / sqrtf(s * (1.0f / kRANK) + 1e-6f);
}

// ---------------------------------------------------------------------------
extern "C" void kernel_launch(void* const* d_in, const int* in_sizes, int n_in,
                              void* d_out, int out_size, void* d_ws, size_t ws_size,
                              hipStream_t stream)
{
    const float* x    = (const float*)d_in[0];
    const float* Wq   = (const float*)d_in[1];
    const float* Wck  = (const float*)d_in[2];
    const float* Wcv  = (const float*)d_in[3];
    const float* Wcg  = (const float*)d_in[4];
    const float* ape_c= (const float*)d_in[5];
    const float* Wiq  = (const float*)d_in[6];
    const float* Wik  = (const float*)d_in[7];
    const float* Wig  = (const float*)d_in[8];
    const float* ape_i= (const float*)d_in[9];
    const float* Wa   = (const float*)d_in[10];
    const float* Wb   = (const float*)d_in[11];
    float* out = (float*)d_out;

    const int M = kB * kT;  // 8192

    // Workspace carve (~222 MB).
    // P (fp64, 100.7 MB) is dead after isc_f64; Y (fp32, 83.9 MB) aliases it.
    char* p = (char*)d_ws;
    double* P       = (double*)p;              p += (size_t)M * PLD * 8;        // 100.7 MB
    double* ikeys64 = (double*)p;              p += (size_t)kB * kG * 512 * 8;  //   8.4 MB
    double* isc64   = (double*)p;              p += (size_t)M * kG * 8;         //  33.6 MB
    float* ck       = (float*)p;               p += (size_t)kB * kG * kHKV * kD * 4;
    float* cv       = (float*)p;               p += (size_t)kB * kG * kHKV * kD * 4;
    float* rbuf     = (float*)p;               p += (size_t)M * kRANK * 4;      //  16.8 MB
    float* rscale   = (float*)p;               p += (size_t)M * 4;
    int* sel        = (int*)p;                 p += (size_t)M * kTOPK * 4;
    int* cnt        = (int*)p;                 p += (size_t)M * 4;
    unsigned short* xcat  = (unsigned short*)p; p += (size_t)M * 2048 * 2;      //  33.6 MB
    unsigned short* Wtall = (unsigned short*)p; p += (size_t)NTOT * 2048 * 2;   //  10.5 MB
    unsigned short* Wat   = (unsigned short*)p; p += (size_t)kRANK * 2048 * 2;
    unsigned short* Wbt   = (unsigned short*)p; p += (size_t)kC * 1024 * 2;
    float* Wcat     = (float*)p;               p += (size_t)kC * PLD * 4;       //   6.3 MB
    // Aliases (lifetime-disjoint):
    float* Y = (float*)P;
    unsigned short* acat  = xcat;
    unsigned short* rncat = (unsigned short*)isc64;

    // --- fp64 indexer chain (must finish before Y overwrites P) ---
    concat_w_kernel<<<(kC * PLD / 4) / 256, 256, 0, stream>>>(Wiq, Wik, Wig, Wcat);
    proj_f64_kernel<<<dim3(PLD / PBN, M / PBM), 256, 0, stream>>>(x, Wcat, P);
    gate_i_kernel<<<kB * kG * kHI, 64, 0, stream>>>(P, ape_i, ikeys64);
    rmsiq64_kernel<<<M, 512, 0, stream>>>(P);
    isc_f64_kernel<<<dim3(kG / BN, M / BM), 256, 0, stream>>>(P, ikeys64, isc64);
    topk_kernel<<<kB * kT, 256, 0, stream>>>(isc64, sel, cnt);

    // --- value path ---
    split_rows_kernel<<<(size_t)M * kC / 4 / 256, 256, 0, stream>>>(
        x, xcat, kC, 8, nullptr);
    transpose_split_kernel<<<dim3(kC / 64, 1024 / 64), 256, 0, stream>>>(
        Wq, 1024, kC, Wtall + (size_t)Q_OFF * 2048);
    transpose_split_kernel<<<dim3(kC / 64, 512 / 64), 256, 0, stream>>>(
        Wck, 512, kC, Wtall + (size_t)CK_OFF * 2048);
    transpose_split_kernel<<<dim3(kC / 64, 512 / 64), 256, 0, stream>>>(
        Wcv, 512, kC, Wtall + (size_t)CV_OFF * 2048);
    transpose_split_kernel<<<dim3(kC / 64, 512 / 64), 256, 0, stream>>>(
        Wcg, 512, kC, Wtall + (size_t)CG_OFF * 2048);

    gemm_mfma_kernel<<<dim3(NTOT / 128, M / 128), 256, 0, stream>>>(
        xcat, Wtall, Y, NTOT, kC);

    rope_q_kernel<<<(kB * kT * kH * 32) / 256, 256, 0, stream>>>(Y);
    compress_c_kernel<<<kB * kG * kHKV, 128, 0, stream>>>(Y, ape_c, ck, cv);

    attn_kernel<<<kB * kT * kH, 64, 0, stream>>>(Y, ck, cv, sel, cnt, acat);

    split_rows_kernel<<<(size_t)kRANK * kC / 4 / 256, 256, 0, stream>>>(
        Wa, Wat, kC, 8, nullptr);
    gemm_mfma_kernel<<<dim3(kRANK / 128, M / 128), 256, 0, stream>>>(
        acat, Wat, rbuf, kRANK, kC);

    rms_rows_kernel<<<M, 64, 0, stream>>>(rbuf, rscale);
    split_rows_kernel<<<(size_t)M * kRANK / 4 / 256, 256, 0, stream>>>(
        rbuf, rncat, kRANK, 7, rscale);
    transpose_split_kernel<<<dim3(kRANK / 64, kC / 64), 256, 0, stream>>>(
        Wb, kC, kRANK, Wbt);
    gemm_mfma_kernel<<<dim3(kC / 128, M / 128), 256, 0, stream>>>(
        rncat, Wbt, out, kC, kRANK);

    (void)in_sizes; (void)n_in; (void)out_size; (void)ws_size;
}

// Round 6
// 1458.906 us; speedup vs baseline: 2.0122x; 1.0744x over previous
//
#include <hip/hip_runtime.h>
#include <hip/hip_bf16.h>
#include <math.h>

// Problem constants
constexpr int kB = 4, kT = 2048, kC = 1024;
constexpr int kH = 8, kHKV = 4, kD = 128;
constexpr int kRATIO = 4, kG = 512;
constexpr int kHI = 8, kDI = 64;
constexpr int kTOPK = 64, kRANK = 512;
constexpr float kTHETA = 160000.0f;
constexpr float kNEG = -1e30f;

// Projection buffer column layout (value path; indexer path is fp64)
constexpr int NTOT = 2560;
constexpr int Q_OFF = 0;      // 1024 cols (H*D)
constexpr int CK_OFF = 1024;  // 512
constexpr int CV_OFF = 1536;  // 512
constexpr int CG_OFF = 2048;  // 512

// fp64 indexer projection buffer P: 8192 x 1536 (iq | ki | gi)
constexpr int PLD = 1536;
constexpr int P_IQ = 0, P_KI = 512, P_GI = 1024;

typedef short short8 __attribute__((ext_vector_type(8)));
typedef float floatx4 __attribute__((ext_vector_type(4)));

__device__ inline float waveReduceSum(float v) {
    #pragma unroll
    for (int m = 32; m > 0; m >>= 1) v += __shfl_xor(v, m, 64);
    return v;
}
__device__ inline double waveReduceSumD(double v) {
    #pragma unroll
    for (int m = 32; m > 0; m >>= 1) v += __shfl_xor(v, m, 64);
    return v;
}
__device__ inline float waveReduceMax(float v) {
    #pragma unroll
    for (int m = 32; m > 0; m >>= 1) v = fmaxf(v, __shfl_xor(v, m, 64));
    return v;
}

// bf16 round-to-nearest-even (values are finite/well-behaved; no NaN path)
__device__ inline unsigned short f2bf(float f) {
    union { float f; unsigned int u; } v; v.f = f;
    unsigned int r = v.u + 0x7FFFu + ((v.u >> 16) & 1u);
    return (unsigned short)(r >> 16);
}
__device__ inline float bf2f(unsigned short h) {
    union { unsigned int u; float f; } v; v.u = ((unsigned int)h) << 16;
    return v.f;
}

// ---------------------------------------------------------------------------
// split_rows: in (rows x K fp32, optional per-row scale) -> out (rows x 2K bf16)
// ---------------------------------------------------------------------------
__global__ __launch_bounds__(256) void split_rows_kernel(
    const float* __restrict__ in, unsigned short* __restrict__ out,
    int K, int kshift, const float* __restrict__ rowScale)
{
    int idx = blockIdx.x * 256 + threadIdx.x;
    int row = idx >> kshift;
    int kc = (idx & ((1 << kshift) - 1)) << 2;
    float4 v = *(const float4*)(in + (size_t)row * K + kc);
    if (rowScale) {
        float s = rowScale[row];
        v.x *= s; v.y *= s; v.z *= s; v.w *= s;
    }
    unsigned short h[4], l[4];
    float vv[4] = {v.x, v.y, v.z, v.w};
    #pragma unroll
    for (int i = 0; i < 4; ++i) {
        h[i] = f2bf(vv[i]);
        l[i] = f2bf(vv[i] - bf2f(h[i]));
    }
    size_t ob = (size_t)row * (2 * K);
    uint2 hw, lw;
    hw.x = (unsigned)h[0] | ((unsigned)h[1] << 16);
    hw.y = (unsigned)h[2] | ((unsigned)h[3] << 16);
    lw.x = (unsigned)l[0] | ((unsigned)l[1] << 16);
    lw.y = (unsigned)l[2] | ((unsigned)l[3] << 16);
    *(uint2*)(out + ob + kc) = hw;
    *(uint2*)(out + ob + K + kc) = lw;
}

// ---------------------------------------------------------------------------
// transpose_split: W (K x N fp32, row-major) -> Wt (N x 2K bf16) [hi|lo]
// ---------------------------------------------------------------------------
__global__ __launch_bounds__(256) void transpose_split_kernel(
    const float* __restrict__ W, int N, int K, unsigned short* __restrict__ Wt)
{
    __shared__ float Ws[64][68];
    int k0 = blockIdx.x * 64, n0 = blockIdx.y * 64;
    int tid = threadIdx.x;
    #pragma unroll
    for (int it = 0; it < 4; ++it) {
        int krow = (tid >> 4) + it * 16;
        float4 v = *(const float4*)(W + (size_t)(k0 + krow) * N + n0 + (tid & 15) * 4);
        *(float4*)&Ws[krow][(tid & 15) * 4] = v;
    }
    __syncthreads();
    #pragma unroll
    for (int it = 0; it < 2; ++it) {
        int idx = tid + it * 256;
        int nrow = idx >> 3;
        int kc8 = (idx & 7) * 8;
        unsigned short h[8], l[8];
        #pragma unroll
        for (int j = 0; j < 8; ++j) {
            float v = Ws[kc8 + j][nrow];
            h[j] = f2bf(v);
            l[j] = f2bf(v - bf2f(h[j]));
        }
        size_t ob = (size_t)(n0 + nrow) * (2 * K) + k0;
        uint4 hw, lw;
        hw.x = (unsigned)h[0] | ((unsigned)h[1] << 16);
        hw.y = (unsigned)h[2] | ((unsigned)h[3] << 16);
        hw.z = (unsigned)h[4] | ((unsigned)h[5] << 16);
        hw.w = (unsigned)h[6] | ((unsigned)h[7] << 16);
        lw.x = (unsigned)l[0] | ((unsigned)l[1] << 16);
        lw.y = (unsigned)l[2] | ((unsigned)l[3] << 16);
        lw.z = (unsigned)l[4] | ((unsigned)l[5] << 16);
        lw.w = (unsigned)l[6] | ((unsigned)l[7] << 16);
        *(uint4*)(Wt + ob + kc8) = hw;
        *(uint4*)(Wt + ob + K + kc8) = lw;
    }
}

// ---------------------------------------------------------------------------
// Split-bf16 MFMA GEMM: C(MxN f32) = A * B^T using bf16 16x16x32 MFMA.
// K' = 3*Kin passes: [A_hi*B_hi, A_lo*B_hi, A_hi*B_lo] -> fp32-grade.
// ---------------------------------------------------------------------------
#define TSTRIDE 40  // 32 bf16 + 8 pad

__global__ __launch_bounds__(256) void gemm_mfma_kernel(
    const unsigned short* __restrict__ A,
    const unsigned short* __restrict__ B,
    float* __restrict__ C, int ldc, int Kin)
{
    __shared__ unsigned short As[128 * TSTRIDE];
    __shared__ unsigned short Bs[128 * TSTRIDE];
    const int tid = threadIdx.x;
    const int n0 = blockIdx.x * 128, m0 = blockIdx.y * 128;
    const int w = tid >> 6, lane = tid & 63;
    const int q = lane >> 4, r = lane & 15;
    const int wm = (w & 1) * 64, wn = (w >> 1) * 64;
    const int lda = 2 * Kin, ldb = 2 * Kin;
    const int srow = tid >> 2;
    const int sko = (tid & 3) * 8;

    floatx4 acc[4][4] = {};
    const int KT = 3 * Kin;
    for (int k0 = 0; k0 < KT; k0 += 32) {
        int ka = (k0 < 2 * Kin) ? k0 : k0 - 2 * Kin;
        int kb = (k0 < Kin) ? k0 : k0 - Kin;
        __syncthreads();
        #pragma unroll
        for (int rep = 0; rep < 2; ++rep) {
            int row = srow + rep * 64;
            uint4 av = *(const uint4*)(A + (size_t)(m0 + row) * lda + ka + sko);
            uint4 bv = *(const uint4*)(B + (size_t)(n0 + row) * ldb + kb + sko);
            *(uint4*)&As[row * TSTRIDE + sko] = av;
            *(uint4*)&Bs[row * TSTRIDE + sko] = bv;
        }
        __syncthreads();
        short8 af[4], bf[4];
        #pragma unroll
        for (int i = 0; i < 4; ++i)
            af[i] = *(const short8*)&As[(wm + i * 16 + r) * TSTRIDE + q * 8];
        #pragma unroll
        for (int j = 0; j < 4; ++j)
            bf[j] = *(const short8*)&Bs[(wn + j * 16 + r) * TSTRIDE + q * 8];
        #pragma unroll
        for (int i = 0; i < 4; ++i)
            #pragma unroll
            for (int j = 0; j < 4; ++j)
                acc[i][j] = __builtin_amdgcn_mfma_f32_16x16x32_bf16(
                    af[i], bf[j], acc[i][j], 0, 0, 0);
    }
    #pragma unroll
    for (int i = 0; i < 4; ++i)
        #pragma unroll
        for (int j = 0; j < 4; ++j)
            #pragma unroll
            for (int reg = 0; reg < 4; ++reg)
                C[(size_t)(m0 + wm + i * 16 + q * 4 + reg) * ldc
                  + n0 + wn + j * 16 + r] = acc[i][j][reg];
}

// ---------------------------------------------------------------------------
// In-place partial RoPE on q columns of Y.
// ---------------------------------------------------------------------------
__global__ __launch_bounds__(256) void rope_q_kernel(float* __restrict__ Y)
{
    int idx = blockIdx.x * 256 + threadIdx.x;
    int j = idx & 31;
    int rest = idx >> 5;
    int h = rest & 7;  rest >>= 3;
    int t = rest & (kT - 1);
    int b = rest >> 11;
    size_t base = (size_t)(b * kT + t) * NTOT + Q_OFF + h * kD;
    float inv_freq = powf(kTHETA, -(float)j * (1.0f / 32.0f));
    float ang = (float)t * inv_freq;
    float c = cosf(ang), s = sinf(ang);
    float x1 = Y[base + 64 + j];
    float x2 = Y[base + 96 + j];
    Y[base + 64 + j] = x1 * c - x2 * s;
    Y[base + 96 + j] = x1 * s + x2 * c;
}

// Gated compress for main KV + RoPE on ck. One block(128) per (b,g,h in HKV).
__global__ __launch_bounds__(128) void compress_c_kernel(
    const float* __restrict__ Y, const float* __restrict__ ape_c,
    float* __restrict__ ck, float* __restrict__ cv)
{
    int bid = blockIdx.x;
    int h = bid & 3;
    int g = (bid >> 2) & (kG - 1);
    int b = bid >> 11;
    int d = threadIdx.x;
    float kv[kRATIO], vv[kRATIO], gv[kRATIO];
    #pragma unroll
    for (int r = 0; r < kRATIO; ++r) {
        size_t row = (size_t)(b * kT + g * kRATIO + r) * NTOT;
        kv[r] = Y[row + CK_OFF + h * kD + d];
        vv[r] = Y[row + CV_OFF + h * kD + d];
        gv[r] = Y[row + CG_OFF + h * kD + d] + ape_c[(r * kHKV + h) * kD + d];
    }
    float m = fmaxf(fmaxf(gv[0], gv[1]), fmaxf(gv[2], gv[3]));
    float ka = 0.f, va = 0.f, den = 0.f;
    #pragma unroll
    for (int r = 0; r < kRATIO; ++r) {
        float e = expf(gv[r] - m);
        den += e;
        ka += kv[r] * e;
        va += vv[r] * e;
    }
    ka /= den; va /= den;
    size_t obase = ((size_t)(b * kG + g) * kHKV + h) * kD;
    cv[obase + d] = va;
    __shared__ float cks[kD];
    cks[d] = ka;
    __syncthreads();
    int pos = 4 * g + 3;
    float out;
    if (d < 64) {
        out = cks[d];
    } else if (d < 96) {
        int j = d - 64;
        float inv_freq = powf(kTHETA, -(float)j * (1.0f / 32.0f));
        float ang = (float)pos * inv_freq;
        out = cks[d] * cosf(ang) - cks[d + 32] * sinf(ang);
    } else {
        int j = d - 96;
        float inv_freq = powf(kTHETA, -(float)j * (1.0f / 32.0f));
        float ang = (float)pos * inv_freq;
        out = cks[d - 32] * sinf(ang) + cks[d] * cosf(ang);
    }
    ck[obase + d] = out;
}

// ---------------------------------------------------------------------------
// Weight concat for the fp64 indexer GEMM: Wcat = [Wiq | Wik | Wig] (1024x1536)
// ---------------------------------------------------------------------------
__global__ __launch_bounds__(256) void concat_w_kernel(
    const float* __restrict__ Wiq, const float* __restrict__ Wik,
    const float* __restrict__ Wig, float* __restrict__ Wcat)
{
    int idx = blockIdx.x * 256 + threadIdx.x;
    int row = idx / 384;
    int col = (idx - row * 384) * 4;
    float4 v;
    if (col < 512)       v = *(const float4*)(Wiq + (size_t)row * 512 + col);
    else if (col < 1024) v = *(const float4*)(Wik + (size_t)row * 512 + col - 512);
    else                 v = *(const float4*)(Wig + (size_t)row * 512 + col - 1024);
    *(float4*)(Wcat + (size_t)row * PLD + col) = v;
}

// ---------------------------------------------------------------------------
// Tiled fp64 GEMM: P(8192x1536 f64) = x(8192x1024 f32) @ Wcat(1024x1536 f32).
// 128x128 tile, 8x8 micro-tile: 64 FMA per 16 LDS reads (2x R5's ratio).
// Micro-reads conflict-free: A = 4-address broadcast (2-way, free);
// B cols tx+16*j -> 16 consecutive doubles = 16 distinct banks.
// ---------------------------------------------------------------------------
#define PBM 128
#define PBN 128
#define PBK 16

__global__ __launch_bounds__(256, 2) void proj_f64_kernel(
    const float* __restrict__ x, const float* __restrict__ W,
    double* __restrict__ P)
{
    __shared__ double As[PBK][PBM + 1];   // 16.5 KB
    __shared__ double Bs[PBK][PBN + 8];   // 17.4 KB
    const int tid = threadIdx.x;
    const int bx = blockIdx.x, by = blockIdx.y;
    const int tx = tid & 15, ty = tid >> 4;
    const int ar = tid >> 1;              // 0..127
    const int ak = (tid & 1) * 8;
    const int br = tid >> 4;              // 0..15
    const int bc = tid & 15;
    const float* Ap = x + (size_t)(by * PBM + ar) * kC + ak;
    const float* Bp = W + (size_t)br * PLD + bx * PBN + bc;
    double acc[8][8] = {};
    for (int k0 = 0; k0 < kC; k0 += PBK) {
        float4 a0 = *(const float4*)(Ap + k0);
        float4 a1 = *(const float4*)(Ap + k0 + 4);
        const float* bp = Bp + (size_t)k0 * PLD;
        float bv[8];
        #pragma unroll
        for (int i = 0; i < 8; ++i) bv[i] = bp[16 * i];
        __syncthreads();
        As[ak + 0][ar] = (double)a0.x;
        As[ak + 1][ar] = (double)a0.y;
        As[ak + 2][ar] = (double)a0.z;
        As[ak + 3][ar] = (double)a0.w;
        As[ak + 4][ar] = (double)a1.x;
        As[ak + 5][ar] = (double)a1.y;
        As[ak + 6][ar] = (double)a1.z;
        As[ak + 7][ar] = (double)a1.w;
        #pragma unroll
        for (int i = 0; i < 8; ++i) Bs[br][bc + 16 * i] = (double)bv[i];
        __syncthreads();
        #pragma unroll
        for (int kk = 0; kk < PBK; ++kk) {
            double a[8], b[8];
            #pragma unroll
            for (int i = 0; i < 8; ++i) a[i] = As[kk][ty * 8 + i];
            #pragma unroll
            for (int j = 0; j < 8; ++j) b[j] = Bs[kk][tx + 16 * j];
            #pragma unroll
            for (int i = 0; i < 8; ++i)
                #pragma unroll
                for (int j = 0; j < 8; ++j)
                    acc[i][j] = fma(a[i], b[j], acc[i][j]);
        }
    }
    #pragma unroll
    for (int i = 0; i < 8; ++i)
        #pragma unroll
        for (int j = 0; j < 8; ++j)
            P[(size_t)(by * PBM + ty * 8 + i) * PLD + bx * PBN + tx + 16 * j] = acc[i][j];
}

// Gating epilogue: ikeys64[b,g,h,:] = rmsnorm(sum_r ki*softmax(gi+ape)).
__global__ __launch_bounds__(64) void gate_i_kernel(
    const double* __restrict__ P, const float* __restrict__ ape_i,
    double* __restrict__ ikeys64)
{
    int bid = blockIdx.x;              // (b*512+g)*8+h
    int h = bid & 7;
    int g = (bid >> 3) & (kG - 1);
    int b = bid >> 12;
    int lane = threadIdx.x;
    double kk[kRATIO], gg[kRATIO];
    #pragma unroll
    for (int r = 0; r < kRATIO; ++r) {
        size_t row = (size_t)(b * kT + g * kRATIO + r) * PLD;
        kk[r] = P[row + P_KI + h * kDI + lane];
        gg[r] = P[row + P_GI + h * kDI + lane] + (double)ape_i[(r * kHI + h) * kDI + lane];
    }
    double m = fmax(fmax(gg[0], gg[1]), fmax(gg[2], gg[3]));
    double acc = 0.0, den = 0.0;
    #pragma unroll
    for (int r = 0; r < kRATIO; ++r) {
        double e = exp(gg[r] - m);
        den += e;
        acc += kk[r] * e;
    }
    acc /= den;
    double ss = waveReduceSumD(acc * acc);
    double scale = 1.0 / sqrt(ss * (1.0 / kDI) + 1e-6);
    ikeys64[((size_t)(b * kG + g) * kHI + h) * kDI + lane] = acc * scale;
}

// rmsnorm iq columns of P in place (per (row,h) over DI=64). Block=512 (8 waves).
__global__ __launch_bounds__(512) void rmsiq64_kernel(double* __restrict__ P)
{
    int row = blockIdx.x;
    int tid = threadIdx.x;
    double* p = P + (size_t)row * PLD + P_IQ + tid;
    double v = *p;
    double ss = v * v;
    #pragma unroll
    for (int m = 32; m > 0; m >>= 1) ss += __shfl_xor(ss, m, 64);
    double scale = 1.0 / sqrt(ss * (1.0 / kDI) + 1e-6);
    *p = v * scale;
}

// ---------------------------------------------------------------------------
// isc64 = (iq @ ikeys^T)/64 per batch. 64x128 tile, 4x8 micro, fp64.
// A = P (lda PLD), B = ikeys64 (NT, ldb 512).
// ---------------------------------------------------------------------------
__global__ __launch_bounds__(256, 2) void isc_f64_kernel(
    const double* __restrict__ P, const double* __restrict__ ikeys64,
    double* __restrict__ isc64)
{
    __shared__ double As[16][65];
    __shared__ double Bs[16][136];
    const int tid = threadIdx.x;
    const int bx = blockIdx.x, by = blockIdx.y;   // bx: 0..3 (n-tile), by: 0..127
    const int b = by >> 5;                        // 32 row-tiles of 64 per batch
    const int tx = tid & 15, ty = tid >> 4;
    const int ar = tid >> 2;                      // 0..63
    const int ak = (tid & 3) * 4;
    const int bn = tid >> 1;                      // 0..127
    const int bk = (tid & 1) * 8;
    const double* Ap = P + (size_t)(by * 64 + ar) * PLD + P_IQ + ak;
    const double* Bp = ikeys64 + (size_t)b * kG * 512
                     + (size_t)(bx * 128 + bn) * 512 + bk;
    double acc[4][8] = {};
    for (int k0 = 0; k0 < 512; k0 += 16) {
        double av[4], bv[8];
        #pragma unroll
        for (int i = 0; i < 4; ++i) av[i] = Ap[k0 + i];
        #pragma unroll
        for (int i = 0; i < 8; ++i) bv[i] = Bp[k0 + i];
        __syncthreads();
        #pragma unroll
        for (int i = 0; i < 4; ++i) As[ak + i][ar] = av[i];
        #pragma unroll
        for (int i = 0; i < 8; ++i) Bs[bk + i][bn] = bv[i];
        __syncthreads();
        #pragma unroll
        for (int kk = 0; kk < 16; ++kk) {
            double a[4], b2[8];
            #pragma unroll
            for (int i = 0; i < 4; ++i) a[i] = As[kk][ty * 4 + i];
            #pragma unroll
            for (int j = 0; j < 8; ++j) b2[j] = Bs[kk][tx + 16 * j];
            #pragma unroll
            for (int i = 0; i < 4; ++i)
                #pragma unroll
                for (int j = 0; j < 8; ++j)
                    acc[i][j] = fma(a[i], b2[j], acc[i][j]);
        }
    }
    #pragma unroll
    for (int i = 0; i < 4; ++i)
        #pragma unroll
        for (int j = 0; j < 8; ++j)
            isc64[(size_t)(by * 64 + ty * 4 + i) * kG + bx * 128 + tx + 16 * j] =
                acc[i][j] * (1.0 / 64.0);
}

// ---------------------------------------------------------------------------
// Top-k via bitonic sort on uint64 keys (group idx in low 9 bits).
// ---------------------------------------------------------------------------
__global__ __launch_bounds__(256) void topk_kernel(
    const double* __restrict__ isc, int* __restrict__ sel, int* __restrict__ cnt)
{
    int bt = blockIdx.x;
    int t = bt & (kT - 1);
    int tid = threadIdx.x;
    __shared__ unsigned long long sk[kG];
    const double* row = isc + (size_t)bt * kG;
    for (int g = tid; g < kG; g += 256) {
        bool causal = (4 * g + 3) <= t;
        unsigned long long key;
        if (causal) {
            union { double d; unsigned long long u; } v; v.d = row[g];
            unsigned long long b = v.u;
            key = (b >> 63) ? ~b : (b | 0x8000000000000000ULL);
            key = (key & ~511ULL) | (unsigned long long)(511 - g);
        } else {
            key = (unsigned long long)(511 - g);
        }
        sk[g] = key;
    }
    __syncthreads();
    for (int k = 2; k <= kG; k <<= 1) {
        for (int j = k >> 1; j > 0; j >>= 1) {
            #pragma unroll 2
            for (int i = tid; i < kG; i += 256) {
                int l = i ^ j;
                if (l > i) {
                    unsigned long long ki = sk[i], kl = sk[l];
                    bool l_first = kl > ki;
                    bool desc = ((i & k) == 0);
                    if (desc ? l_first : !l_first) {
                        sk[i] = kl; sk[l] = ki;
                    }
                }
            }
            __syncthreads();
        }
    }
    int count = (t >= 3) ? (((t - 3) >> 2) + 1) : 0;
    int n = count < kTOPK ? count : kTOPK;
    if (tid < kTOPK)
        sel[(size_t)bt * kTOPK + tid] =
            (tid < n) ? (511 - (int)(sk[tid] & 511ULL)) : 0;
    if (tid == 0) cnt[bt] = n;
}

// ---------------------------------------------------------------------------
// Sparse gathered attention: one block(256) per (b,t); wave w computes the
// head pair {2w, 2w+1} sharing kvh=w -> ck/cv read once per pair.
// Softmax weights broadcast via __shfl (no LDS round-trip).
// ---------------------------------------------------------------------------
__global__ __launch_bounds__(256) void attn_kernel(
    const float* __restrict__ Y, const float* __restrict__ ck,
    const float* __restrict__ cv, const int* __restrict__ sel,
    const int* __restrict__ cnt, unsigned short* __restrict__ acat)
{
    int row = blockIdx.x;              // b*T + t
    int b = row >> 11;
    int tid = threadIdx.x;
    int w = tid >> 6, lane = tid & 63;
    __shared__ float qs[kC];
    const float* qp = Y + (size_t)row * NTOT + Q_OFF;
    *(float4*)&qs[tid * 4] = *(const float4*)&qp[tid * 4];
    __syncthreads();
    int n = cnt[row];
    int h0 = 2 * w, h1 = 2 * w + 1, kvh = w;
    float sc0 = kNEG, sc1 = kNEG;
    int g = 0;
    if (lane < n) {
        g = sel[(size_t)row * kTOPK + lane];
        const float* ckp = ck + ((size_t)(b * kG + g) * kHKV + kvh) * kD;
        float s0 = 0.f, s1 = 0.f;
        #pragma unroll
        for (int d = 0; d < kD; d += 4) {
            float4 c4 = *(const float4*)(ckp + d);
            float4 q0 = *(const float4*)&qs[h0 * kD + d];
            float4 q1 = *(const float4*)&qs[h1 * kD + d];
            s0 += q0.x * c4.x + q0.y * c4.y + q0.z * c4.z + q0.w * c4.w;
            s1 += q1.x * c4.x + q1.y * c4.y + q1.z * c4.z + q1.w * c4.w;
        }
        sc0 = s0 * 0.08838834764831845f;
        sc1 = s1 * 0.08838834764831845f;
    }
    float m0 = waveReduceMax(sc0), m1 = waveReduceMax(sc1);
    float p0 = (lane < n) ? expf(sc0 - m0) : 0.f;
    float p1 = (lane < n) ? expf(sc1 - m1) : 0.f;
    float sum0 = waveReduceSum(p0), sum1 = waveReduceSum(p1);
    float w0 = p0 / sum0, w1 = p1 / sum1;   // nan if n==0, unused then
    float acc00 = 0.f, acc01 = 0.f, acc10 = 0.f, acc11 = 0.f;
    for (int j = 0; j < n; ++j) {
        float wj0 = __shfl(w0, j, 64);
        float wj1 = __shfl(w1, j, 64);
        int gj = __shfl(g, j, 64);
        const float* cvp = cv + ((size_t)(b * kG + gj) * kHKV + kvh) * kD;
        float v0 = cvp[lane], v1 = cvp[lane + 64];
        acc00 = fmaf(wj0, v0, acc00);
        acc01 = fmaf(wj0, v1, acc01);
        acc10 = fmaf(wj1, v0, acc10);
        acc11 = fmaf(wj1, v1, acc11);
    }
    unsigned short* outp0 = acat + (size_t)row * 2048 + h0 * kD;
    unsigned short* outp1 = acat + (size_t)row * 2048 + h1 * kD;
    unsigned short a0 = f2bf(acc00), a1 = f2bf(acc01);
    unsigned short b0 = f2bf(acc10), b1 = f2bf(acc11);
    outp0[lane] = a0;           outp0[lane + 64] = a1;
    outp0[1024 + lane] = f2bf(acc00 - bf2f(a0));
    outp0[1024 + lane + 64] = f2bf(acc01 - bf2f(a1));
    outp1[lane] = b0;           outp1[lane + 64] = b1;
    outp1[1024 + lane] = f2bf(acc10 - bf2f(b0));
    outp1[1024 + lane + 64] = f2bf(acc11 - bf2f(b1));
}

// Row rms scales for r (RANK=512 per row). One wave per row.
__global__ __launch_bounds__(64) void rms_rows_kernel(
    const float* __restrict__ R, float* __restrict__ scale)
{
    int row = blockIdx.x;
    int lane = threadIdx.x;
    const float* p = R + (size_t)row * kRANK;
    float s = 0.f;
    #pragma unroll
    for (int i = 0; i < kRANK / 64; ++i) {
        float v = p[lane + i * 64];
        s = fmaf(v, v, s);
    }
    s = waveReduceSum(s);
    if (lane == 0) scale[row] = 1.0f / sqrtf(s * (1.0f / kRANK) + 1e-6f);
}

// ---------------------------------------------------------------------------
extern "C" void kernel_launch(void* const* d_in, const int* in_sizes, int n_in,
                              void* d_out, int out_size, void* d_ws, size_t ws_size,
                              hipStream_t stream)
{
    const float* x    = (const float*)d_in[0];
    const float* Wq   = (const float*)d_in[1];
    const float* Wck  = (const float*)d_in[2];
    const float* Wcv  = (const float*)d_in[3];
    const float* Wcg  = (const float*)d_in[4];
    const float* ape_c= (const float*)d_in[5];
    const float* Wiq  = (const float*)d_in[6];
    const float* Wik  = (const float*)d_in[7];
    const float* Wig  = (const float*)d_in[8];
    const float* ape_i= (const float*)d_in[9];
    const float* Wa   = (const float*)d_in[10];
    const float* Wb   = (const float*)d_in[11];
    float* out = (float*)d_out;

    const int M = kB * kT;  // 8192

    // Workspace carve (~222 MB). P dead after isc_f64; Y aliases it.
    char* p = (char*)d_ws;
    double* P       = (double*)p;              p += (size_t)M * PLD * 8;
    double* ikeys64 = (double*)p;              p += (size_t)kB * kG * 512 * 8;
    double* isc64   = (double*)p;              p += (size_t)M * kG * 8;
    float* ck       = (float*)p;               p += (size_t)kB * kG * kHKV * kD * 4;
    float* cv       = (float*)p;               p += (size_t)kB * kG * kHKV * kD * 4;
    float* rbuf     = (float*)p;               p += (size_t)M * kRANK * 4;
    float* rscale   = (float*)p;               p += (size_t)M * 4;
    int* sel        = (int*)p;                 p += (size_t)M * kTOPK * 4;
    int* cnt        = (int*)p;                 p += (size_t)M * 4;
    unsigned short* xcat  = (unsigned short*)p; p += (size_t)M * 2048 * 2;
    unsigned short* Wtall = (unsigned short*)p; p += (size_t)NTOT * 2048 * 2;
    unsigned short* Wat   = (unsigned short*)p; p += (size_t)kRANK * 2048 * 2;
    unsigned short* Wbt   = (unsigned short*)p; p += (size_t)kC * 1024 * 2;
    float* Wcat     = (float*)p;               p += (size_t)kC * PLD * 4;
    // Aliases (lifetime-disjoint):
    float* Y = (float*)P;
    unsigned short* acat  = xcat;
    unsigned short* rncat = (unsigned short*)isc64;

    // --- fp64 indexer chain (must finish before Y overwrites P) ---
    concat_w_kernel<<<(kC * PLD / 4) / 256, 256, 0, stream>>>(Wiq, Wik, Wig, Wcat);
    proj_f64_kernel<<<dim3(PLD / PBN, M / PBM), 256, 0, stream>>>(x, Wcat, P);
    gate_i_kernel<<<kB * kG * kHI, 64, 0, stream>>>(P, ape_i, ikeys64);
    rmsiq64_kernel<<<M, 512, 0, stream>>>(P);
    isc_f64_kernel<<<dim3(kG / 128, M / 64), 256, 0, stream>>>(P, ikeys64, isc64);
    topk_kernel<<<kB * kT, 256, 0, stream>>>(isc64, sel, cnt);

    // --- value path ---
    split_rows_kernel<<<(size_t)M * kC / 4 / 256, 256, 0, stream>>>(
        x, xcat, kC, 8, nullptr);
    transpose_split_kernel<<<dim3(kC / 64, 1024 / 64), 256, 0, stream>>>(
        Wq, 1024, kC, Wtall + (size_t)Q_OFF * 2048);
    transpose_split_kernel<<<dim3(kC / 64, 512 / 64), 256, 0, stream>>>(
        Wck, 512, kC, Wtall + (size_t)CK_OFF * 2048);
    transpose_split_kernel<<<dim3(kC / 64, 512 / 64), 256, 0, stream>>>(
        Wcv, 512, kC, Wtall + (size_t)CV_OFF * 2048);
    transpose_split_kernel<<<dim3(kC / 64, 512 / 64), 256, 0, stream>>>(
        Wcg, 512, kC, Wtall + (size_t)CG_OFF * 2048);

    gemm_mfma_kernel<<<dim3(NTOT / 128, M / 128), 256, 0, stream>>>(
        xcat, Wtall, Y, NTOT, kC);

    rope_q_kernel<<<(kB * kT * kH * 32) / 256, 256, 0, stream>>>(Y);
    compress_c_kernel<<<kB * kG * kHKV, 128, 0, stream>>>(Y, ape_c, ck, cv);

    attn_kernel<<<kB * kT, 256, 0, stream>>>(Y, ck, cv, sel, cnt, acat);

    split_rows_kernel<<<(size_t)kRANK * kC / 4 / 256, 256, 0, stream>>>(
        Wa, Wat, kC, 8, nullptr);
    gemm_mfma_kernel<<<dim3(kRANK / 128, M / 128), 256, 0, stream>>>(
        acat, Wat, rbuf, kRANK, kC);

    rms_rows_kernel<<<M, 64, 0, stream>>>(rbuf, rscale);
    split_rows_kernel<<<(size_t)M * kRANK / 4 / 256, 256, 0, stream>>>(
        rbuf, rncat, kRANK, 7, rscale);
    transpose_split_kernel<<<dim3(kRANK / 64, kC / 64), 256, 0, stream>>>(
        Wb, kC, kRANK, Wbt);
    gemm_mfma_kernel<<<dim3(kC / 128, M / 128), 256, 0, stream>>>(
        rncat, Wbt, out, kC, kRANK);

    (void)in_sizes; (void)n_in; (void)out_size; (void)ws_size;
}